// Round 8
// baseline (182.736 us; speedup 1.0000x reference)
//
#include <hip/hip_runtime.h>
#include <hip/hip_bf16.h>
#include <math.h>

// GuidedAttention: B=4, TA=TV=1024, D=512, H=8, HD=64. All I/O fp32.
// bf16 MFMA internally, fp32 accumulate.
// Round 8: flash split-K attention (ks=2, 1024 blocks -> ~3 blocks/CU) +
// attn_combine merge kernel; gemm_out stores bf16 (ln reads bf16).
typedef __bf16 bf16_t;
typedef _Float16 hf16_t;
typedef bf16_t bf16x8 __attribute__((ext_vector_type(8)));
typedef hf16_t hf16x8 __attribute__((ext_vector_type(8)));
typedef float f32x4 __attribute__((ext_vector_type(4)));

#define B_  4
#define TA_ 1024
#define TV_ 1024
#define D_  512
#define H_  8
#define HD_ 64
#define SCALE_ 0.125f

// async global->LDS copy, 16 B per lane (global_load_lds_dwordx4).
__device__ inline void g2l16(const void* g, void* l) {
    __builtin_amdgcn_global_load_lds(
        (const __attribute__((address_space(1))) void*)g,
        (__attribute__((address_space(3))) void*)l, 16, 0, 0);
}

// ---- DPP cross-lane reductions over 16-lane rows (VALU, not LDS pipe) ----
template <int CTRL>
__device__ inline float dppmov(float x) {
    int xi = __float_as_int(x);
    return __int_as_float(__builtin_amdgcn_update_dpp(xi, xi, CTRL, 0xF, 0xF, false));
}
__device__ inline float row16_max(float x) {
    x = fmaxf(x, dppmov<0xB1>(x));   // quad_perm xor1
    x = fmaxf(x, dppmov<0x4E>(x));   // quad_perm xor2
    x = fmaxf(x, dppmov<0x141>(x));  // row_half_mirror (xor7)
    x = fmaxf(x, dppmov<0x140>(x));  // row_mirror (xor15)
    return x;
}
__device__ inline float row16_sum(float x) {
    x += dppmov<0xB1>(x);
    x += dppmov<0x4E>(x);
    x += dppmov<0x141>(x);
    x += dppmov<0x140>(x);
    return x;
}

// ---- fused prep: blocks [0,1024) = bias tiling; [1024, 4608) = fp32->bf16 cvt.
// bias_t[b][kt][q64][tid][ct*4+r] = log(G[b][qrow][kcol]+1e-8) fp16, C-frag order.
__global__ __launch_bounds__(256) void prep_all(
    const float* __restrict__ G, hf16_t* __restrict__ bias_t,
    const float* __restrict__ q, const float* __restrict__ k, const float* __restrict__ v,
    const float* __restrict__ Wq, const float* __restrict__ Wk,
    const float* __restrict__ Wv, const float* __restrict__ Wo,
    bf16_t* __restrict__ qb, bf16_t* __restrict__ kb, bf16_t* __restrict__ vb,
    bf16_t* __restrict__ Wb)
{
    const int tid = threadIdx.x;
    if (blockIdx.x < 1024) {
        __shared__ float Gt[64][68];
        const int kt = blockIdx.x & 15, q64 = (blockIdx.x >> 4) & 15, b = blockIdx.x >> 8;
        const int row = tid >> 4, col4 = (tid & 15) * 4;
        #pragma unroll
        for (int it = 0; it < 4; ++it) {
            int r = it * 16 + row;
            f32x4 g = *(const f32x4*)(G + ((size_t)(b * TA_ + q64 * 64 + r)) * TV_ + kt * 64 + col4);
            *(f32x4*)&Gt[r][col4] = g;
        }
        __syncthreads();
        const int lane = tid & 63, wave = tid >> 6, quad = lane >> 4, l16 = lane & 15;
        hf16x8 lo, hi;
        #pragma unroll
        for (int ct = 0; ct < 4; ++ct) {
            #pragma unroll
            for (int r = 0; r < 4; ++r) {
                float gv = Gt[wave * 16 + quad * 4 + r][ct * 16 + l16];
                float lb = __logf(gv + 1e-8f);
                int idx = ct * 4 + r;
                if (idx < 8) lo[idx] = (hf16_t)lb; else hi[idx - 8] = (hf16_t)lb;
            }
        }
        size_t doff = ((((size_t)b * 16 + kt) * 16 + q64) * 256 + tid) * 16;
        *(hf16x8*)(bias_t + doff) = lo;
        *(hf16x8*)(bias_t + doff + 8) = hi;
    } else {
        const size_t i = ((size_t)(blockIdx.x - 1024) * 256 + tid) * 8;
        const float* src; bf16_t* dst; size_t off;
        const size_t M2 = (size_t)1 << 21;
        if (i < M2)          { src = q; dst = qb; off = i; }
        else if (i < 2 * M2) { src = k; dst = kb; off = i - M2; }
        else if (i < 3 * M2) { src = v; dst = vb; off = i - 2 * M2; }
        else {
            size_t j = i - 3 * M2;
            int wsel = (int)(j >> 18); off = j & 262143;
            src = (wsel == 0) ? Wq : (wsel == 1) ? Wk : (wsel == 2) ? Wv : Wo;
            dst = Wb + ((size_t)wsel << 18);
        }
        f32x4 a = *(const f32x4*)(src + off), c = *(const f32x4*)(src + off + 4);
        bf16x8 r;
        #pragma unroll
        for (int t = 0; t < 4; ++t) { r[t] = (bf16_t)a[t]; r[t + 4] = (bf16_t)c[t]; }
        *(bf16x8*)(dst + off) = r;
    }
}

// ---- 128x128 LDS-staged GEMM main loop (m97 structure).
__device__ inline void gemm128_core(
    const bf16_t* __restrict__ X, const bf16_t* __restrict__ W,
    int mbase, int nbase, bf16_t (*__restrict__ Asm)[128 * 32],
    bf16_t (*__restrict__ Bsm)[128 * 32], f32x4 acc[4][4])
{
    const int tid  = threadIdx.x;
    const int wave = tid >> 6, lane = tid & 63;
    const int quad = lane >> 4, l16 = lane & 15;
    const int wm = wave & 1, wn = wave >> 1;
    const int srow = lane >> 2;           // staging: 16 rows x 4 chunks of 16B
    const int scol = (lane & 3) * 8;      // elements

    auto stage = [&](int kt, int buf) {
        const int k0 = kt * 32;
        #pragma unroll
        for (int i = 0; i < 2; ++i) {
            const int row = wave * 32 + i * 16;
            g2l16(X + (size_t)(mbase + row + srow) * D_ + k0 + scol,
                  &Asm[buf][row * 32] + (size_t)lane * 8);
            g2l16(W + (size_t)(nbase + row + srow) * D_ + k0 + scol,
                  &Bsm[buf][row * 32] + (size_t)lane * 8);
        }
    };

    stage(0, 0);
    __syncthreads();
    for (int kt = 0; kt < 16; ++kt) {
        const int buf = kt & 1;
        if (kt < 15) stage(kt + 1, buf ^ 1);
        bf16x8 af[4], bf_[4];
        #pragma unroll
        for (int t = 0; t < 4; ++t) {
            af[t]  = *(const bf16x8*)&Asm[buf][(wm * 64 + t * 16 + l16) * 32 + quad * 8];
            bf_[t] = *(const bf16x8*)&Bsm[buf][(wn * 64 + t * 16 + l16) * 32 + quad * 8];
        }
        #pragma unroll
        for (int mt = 0; mt < 4; ++mt) {
            #pragma unroll
            for (int nt = 0; nt < 4; ++nt)
                acc[mt][nt] = __builtin_amdgcn_mfma_f32_16x16x32_bf16(af[mt], bf_[nt], acc[mt][nt], 0, 0, 0);
        }
        __syncthreads();
    }
}

// Fused QKV projection, 128x128 tiles. z=0: qb->Qp [B,H,T,HD]; z=1: kb->Kp; z=2: vb->Vt [B,H,HD,T]
__global__ __launch_bounds__(256) void gemm_qkv(
    const bf16_t* __restrict__ qb, const bf16_t* __restrict__ kb, const bf16_t* __restrict__ vb,
    const bf16_t* __restrict__ Wb,
    const float* __restrict__ bq, const float* __restrict__ bk, const float* __restrict__ bv,
    bf16_t* __restrict__ Qp, bf16_t* __restrict__ Kp, bf16_t* __restrict__ Vt)
{
    __shared__ bf16_t Asm[2][128 * 32];
    __shared__ bf16_t Bsm[2][128 * 32];

    const int tid  = threadIdx.x;
    const int wave = tid >> 6, lane = tid & 63;
    const int quad = lane >> 4, l16 = lane & 15;
    const int wm = wave & 1, wn = wave >> 1;
    const int mbase = blockIdx.x * 128, nbase = blockIdx.y * 128;
    const int z = blockIdx.z;

    const bf16_t* X   = (z == 0) ? qb : (z == 1) ? kb : vb;
    const float* bias = (z == 0) ? bq : (z == 1) ? bk : bv;
    const bf16_t* W   = Wb + ((size_t)z << 18);

    f32x4 acc[4][4] = {};
    gemm128_core(X, W, mbase, nbase, Asm, Bsm, acc);

    bf16_t* out = (z == 0) ? Qp : (z == 1) ? Kp : Vt;
    #pragma unroll
    for (int mt = 0; mt < 4; ++mt) {
        #pragma unroll
        for (int nt = 0; nt < 4; ++nt) {
            #pragma unroll
            for (int r = 0; r < 4; ++r) {
                int m = mbase + wm * 64 + mt * 16 + quad * 4 + r;  // token index
                int n = nbase + wn * 64 + nt * 16 + l16;           // output channel
                float val = acc[mt][nt][r] + bias[n];
                int b = m >> 10, t = m & 1023, h = n >> 6, hd = n & 63;
                if (z != 2)
                    out[(((size_t)(b * H_ + h) * TA_) + t) * HD_ + hd] = (bf16_t)val;
                else
                    out[((size_t)(b * H_ + h) * HD_ + hd) * TV_ + t] = (bf16_t)val;
            }
        }
    }
}

// Out projection, 128x128 tiles: ctx [4096,512] bf16 @ Wo^T + bo -> bf16 [4096,512]
__global__ __launch_bounds__(256) void gemm_out(
    const bf16_t* __restrict__ ctx, const bf16_t* __restrict__ Wob,
    const float* __restrict__ bo, bf16_t* __restrict__ op)
{
    __shared__ bf16_t Asm[2][128 * 32];
    __shared__ bf16_t Bsm[2][128 * 32];

    const int tid  = threadIdx.x;
    const int wave = tid >> 6, lane = tid & 63;
    const int quad = lane >> 4, l16 = lane & 15;
    const int wm = wave & 1, wn = wave >> 1;
    const int mbase = blockIdx.x * 128, nbase = blockIdx.y * 128;

    f32x4 acc[4][4] = {};
    gemm128_core(ctx, Wob, mbase, nbase, Asm, Bsm, acc);

    #pragma unroll
    for (int mt = 0; mt < 4; ++mt) {
        #pragma unroll
        for (int nt = 0; nt < 4; ++nt) {
            #pragma unroll
            for (int r = 0; r < 4; ++r) {
                int m = mbase + wm * 64 + mt * 16 + quad * 4 + r;
                int n = nbase + wn * 64 + nt * 16 + l16;
                op[(size_t)m * D_ + n] = (bf16_t)(acc[mt][nt][r] + bo[n]);
            }
        }
    }
}

// ---- Flash attention, split-K. Qp,Kp: [B,H,T,HD] bf16; Vt: [B,H,HD,TV] bf16;
// bias_t: tiled fp16 (C-frag order). Grid (bh=32, q64=16, ks=2); block = 4 waves,
// wave owns 16 q-rows; block covers k-tiles [z*8, z*8+8).
// Writes unnormalized O partial (bf16, C-frag-linear) + per-row m/l (fp32).
__global__ __launch_bounds__(256) void attn_kernel(
    const bf16_t* __restrict__ Qp, const bf16_t* __restrict__ Kp,
    const bf16_t* __restrict__ Vt, const hf16_t* __restrict__ bias_t,
    const float* __restrict__ bias_scale,
    bf16_t* __restrict__ Opart, float* __restrict__ mpart, float* __restrict__ lpart)
{
    __shared__ bf16_t Ksm[2][64][72];   // [buf][krow][hd]
    __shared__ bf16_t Vsm[2][64][72];   // [buf][hd][kcol]
    __shared__ bf16_t Plds[4][16][72];  // per-wave P tile

    const int tid  = threadIdx.x;
    const int wave = tid >> 6, lane = tid & 63;
    const int quad = lane >> 4, l16 = lane & 15;
    const int bh = blockIdx.x, b = bh >> 3;
    const int q64 = blockIdx.y;
    const int z = blockIdx.z;        // split-K half
    const int t0 = z * 8;            // first k-tile
    const int qbase = q64 * 64 + wave * 16;
    const int rsub = lane >> 3, csub = lane & 7;   // staging: 8 rows x 8 chunks of 16B

    const float sp = log1pf(__expf(bias_scale[0]));  // softplus(bias_scale)

    bf16x8 aq[2];
    #pragma unroll
    for (int s = 0; s < 2; ++s)
        aq[s] = *(const bf16x8*)(Qp + ((size_t)bh * TA_ + qbase + l16) * HD_ + s * 32 + quad * 8);

    f32x4 o[4] = {};
    float m_[4], l_[4];
    #pragma unroll
    for (int i = 0; i < 4; ++i) { m_[i] = -1e30f; l_[i] = 0.f; }

    auto issue_kv = [&](int kt, bf16x8 kr[2], bf16x8 vr[2]) {
        const int kbase = kt * 64;
        #pragma unroll
        for (int i = 0; i < 2; ++i) {
            int row = wave * 16 + i * 8 + rsub;
            kr[i] = *(const bf16x8*)(Kp + ((size_t)bh * TV_ + kbase + row) * HD_ + csub * 8);
            vr[i] = *(const bf16x8*)(Vt + ((size_t)bh * HD_ + row) * TV_ + kbase + csub * 8);
        }
    };
    auto write_kv = [&](int buf, bf16x8 kr[2], bf16x8 vr[2]) {
        #pragma unroll
        for (int i = 0; i < 2; ++i) {
            int row = wave * 16 + i * 8 + rsub;
            *(bf16x8*)&Ksm[buf][row][csub * 8] = kr[i];
            *(bf16x8*)&Vsm[buf][row][csub * 8] = vr[i];
        }
    };

    const hf16_t* bias_base = bias_t + (((size_t)b * 16 * 16 + q64) * 256 + tid) * 16;
    auto bias_ld = [&](int kt, hf16x8& lo, hf16x8& hi) {
        const hf16_t* bp = bias_base + (size_t)kt * 65536;  // kt stride = 16*256*16
        lo = *(const hf16x8*)bp;
        hi = *(const hf16x8*)(bp + 8);
    };
    // static ring slots: slot0 = even local tiles, slot1 = odd
    hf16x8 b0lo, b0hi, b1lo, b1hi;
    bias_ld(t0, b0lo, b0hi);
    bias_ld(t0 + 1, b1lo, b1hi);

    {
        bf16x8 kr[2], vr[2];
        issue_kv(t0, kr, vr);
        write_kv(0, kr, vr);
    }
    __syncthreads();

    // one K-tile; lk = local tile index (0..7), buf literal, static ring slot refs
    auto tile_body = [&](int lk, int buf, hf16x8& slo, hf16x8& shi) {
        const int kt = t0 + lk;
        bf16x8 krn[2], vrn[2];
        if (lk < 7) issue_kv(kt + 1, krn, vrn);
        hf16x8 clo = slo, chi = shi;
        if (lk < 6) bias_ld(kt + 2, slo, shi);

        f32x4 st[4];
        #pragma unroll
        for (int ct = 0; ct < 4; ++ct) {
            f32x4 acc = {};
            #pragma unroll
            for (int s = 0; s < 2; ++s) {
                bf16x8 bk = *(const bf16x8*)&Ksm[buf][ct * 16 + l16][s * 32 + quad * 8];
                acc = __builtin_amdgcn_mfma_f32_16x16x32_bf16(aq[s], bk, acc, 0, 0, 0);
            }
            st[ct] = acc;
        }
        float sv[4][4], mx[4];
        #pragma unroll
        for (int r = 0; r < 4; ++r) mx[r] = -1e30f;
        #pragma unroll
        for (int ct = 0; ct < 4; ++ct) {
            #pragma unroll
            for (int r = 0; r < 4; ++r) {
                int idx = ct * 4 + r;
                float lb = (idx < 8) ? (float)clo[idx] : (float)chi[idx - 8];
                float val = fmaf(lb, sp, st[ct][r] * SCALE_);
                sv[ct][r] = val;
                mx[r] = fmaxf(mx[r], val);
            }
        }
        float alpha[4];
        #pragma unroll
        for (int r = 0; r < 4; ++r) {
            mx[r] = row16_max(mx[r]);
            float mn = fmaxf(m_[r], mx[r]);
            alpha[r] = __expf(m_[r] - mn);
            m_[r] = mn;
        }
        #pragma unroll
        for (int ct = 0; ct < 4; ++ct) {
            #pragma unroll
            for (int r = 0; r < 4; ++r)
                sv[ct][r] = __expf(sv[ct][r] - m_[r]);
        }
        #pragma unroll
        for (int r = 0; r < 4; ++r) {
            float lsum = row16_sum(sv[0][r] + sv[1][r] + sv[2][r] + sv[3][r]);
            l_[r] = l_[r] * alpha[r] + lsum;
        }
        #pragma unroll
        for (int ct = 0; ct < 4; ++ct) {
            #pragma unroll
            for (int r = 0; r < 4; ++r)
                Plds[wave][quad * 4 + r][ct * 16 + l16] = (bf16_t)sv[ct][r];
        }
        #pragma unroll
        for (int dt = 0; dt < 4; ++dt) {
            #pragma unroll
            for (int r = 0; r < 4; ++r) o[dt][r] *= alpha[r];
        }
        #pragma unroll
        for (int s = 0; s < 2; ++s) {
            bf16x8 ap = *(const bf16x8*)&Plds[wave][l16][s * 32 + quad * 8];
            #pragma unroll
            for (int dt = 0; dt < 4; ++dt) {
                bf16x8 bv = *(const bf16x8*)&Vsm[buf][dt * 16 + l16][s * 32 + quad * 8];
                o[dt] = __builtin_amdgcn_mfma_f32_16x16x32_bf16(ap, bv, o[dt], 0, 0, 0);
            }
        }
        if (lk < 7) write_kv(buf ^ 1, krn, vrn);
        __syncthreads();
    };

    #pragma unroll 1
    for (int kk = 0; kk < 8; kk += 2) {
        tile_body(kk,     0, b0lo, b0hi);
        tile_body(kk + 1, 1, b1lo, b1hi);
    }

    // store unnormalized partial O (bf16, C-frag-linear: coalesced 2x16B) + m/l
    const size_t blk = (size_t)bh * 16 + q64;
    bf16x8 plo, phi;
    #pragma unroll
    for (int dt = 0; dt < 4; ++dt) {
        #pragma unroll
        for (int r = 0; r < 4; ++r) {
            int idx = dt * 4 + r;
            if (idx < 8) plo[idx] = (bf16_t)o[dt][r]; else phi[idx - 8] = (bf16_t)o[dt][r];
        }
    }
    size_t poff = (((size_t)z * 512 + blk) * 256 + tid) * 16;
    *(bf16x8*)(Opart + poff) = plo;
    *(bf16x8*)(Opart + poff + 8) = phi;
    if (l16 == 0) {
        #pragma unroll
        for (int r = 0; r < 4; ++r) {
            int row = wave * 16 + quad * 4 + r;
            mpart[((size_t)z * 512 + blk) * 64 + row] = m_[r];
            lpart[((size_t)z * 512 + blk) * 64 + row] = l_[r];
        }
    }
}

// ---- combine the two split-K halves -> ctx [B,TA,D] bf16
__global__ __launch_bounds__(256) void attn_combine(
    const bf16_t* __restrict__ Opart, const float* __restrict__ mpart,
    const float* __restrict__ lpart, bf16_t* __restrict__ ctx)
{
    const int tid  = threadIdx.x;
    const int wave = tid >> 6, lane = tid & 63;
    const int quad = lane >> 4, l16 = lane & 15;
    const int bh = blockIdx.x, b = bh >> 3, h = bh & 7;
    const int q64 = blockIdx.y;
    const size_t blk = (size_t)bh * 16 + q64;

    size_t p0 = (blk * 256 + tid) * 16;
    size_t p1 = (((size_t)512 + blk) * 256 + tid) * 16;
    bf16x8 a0 = *(const bf16x8*)(Opart + p0), a1 = *(const bf16x8*)(Opart + p0 + 8);
    bf16x8 c0 = *(const bf16x8*)(Opart + p1), c1 = *(const bf16x8*)(Opart + p1 + 8);

    float s0[4], s1[4];
    #pragma unroll
    for (int r = 0; r < 4; ++r) {
        int row = wave * 16 + quad * 4 + r;
        float m0 = mpart[blk * 64 + row], m1 = mpart[(512 + blk) * 64 + row];
        float l0 = lpart[blk * 64 + row], l1 = lpart[(512 + blk) * 64 + row];
        float mm = fmaxf(m0, m1);
        float e0 = __expf(m0 - mm), e1 = __expf(m1 - mm);
        float L = l0 * e0 + l1 * e1;
        s0[r] = e0 / L; s1[r] = e1 / L;
    }
    #pragma unroll
    for (int dt = 0; dt < 4; ++dt) {
        #pragma unroll
        for (int r = 0; r < 4; ++r) {
            int idx = dt * 4 + r;
            float v0 = (idx < 8) ? (float)a0[idx] : (float)a1[idx - 8];
            float v1 = (idx < 8) ? (float)c0[idx] : (float)c1[idx - 8];
            float v = v0 * s0[r] + v1 * s1[r];
            int qrow = q64 * 64 + wave * 16 + quad * 4 + r;
            ctx[((size_t)b * TA_ + qrow) * D_ + h * HD_ + dt * 16 + l16] = (bf16_t)v;
        }
    }
}

// y = LayerNorm(q + sigmoid(gate)*out) * gamma + beta, one block per row of 512
__global__ __launch_bounds__(256) void ln_kernel(
    const float* __restrict__ q, const bf16_t* __restrict__ outp,
    const float* __restrict__ gamma, const float* __restrict__ beta,
    const float* __restrict__ gate, float* __restrict__ y)
{
    const int row = blockIdx.x, tid = threadIdx.x;
    const float sg = 1.f / (1.f + __expf(-gate[0]));
    const size_t base = (size_t)row * D_;
    float x0 = q[base + tid]       + sg * (float)outp[base + tid];
    float x1 = q[base + tid + 256] + sg * (float)outp[base + tid + 256];
    float s = x0 + x1, sq = x0 * x0 + x1 * x1;
    #pragma unroll
    for (int off = 1; off < 64; off <<= 1) {
        s  += __shfl_xor(s,  off, 64);
        sq += __shfl_xor(sq, off, 64);
    }
    __shared__ float ss[4], sqq[4];
    if ((tid & 63) == 0) { ss[tid >> 6] = s; sqq[tid >> 6] = sq; }
    __syncthreads();
    s  = ss[0] + ss[1] + ss[2] + ss[3];
    sq = sqq[0] + sqq[1] + sqq[2] + sqq[3];
    const float mu = s * (1.f / D_);
    const float var = sq * (1.f / D_) - mu * mu;
    const float rstd = rsqrtf(var + 1e-5f);
    y[base + tid]       = (x0 - mu) * rstd * gamma[tid] + beta[tid];
    y[base + tid + 256] = (x1 - mu) * rstd * gamma[tid + 256] + beta[tid + 256];
}

extern "C" void kernel_launch(void* const* d_in, const int* in_sizes, int n_in,
                              void* d_out, int out_size, void* d_ws, size_t ws_size,
                              hipStream_t stream) {
    const float* q       = (const float*)d_in[0];
    const float* k       = (const float*)d_in[1];
    const float* v       = (const float*)d_in[2];
    const float* guide   = (const float*)d_in[3];
    const float* Wq      = (const float*)d_in[4];
    const float* bq      = (const float*)d_in[5];
    const float* Wk      = (const float*)d_in[6];
    const float* bk      = (const float*)d_in[7];
    const float* Wv      = (const float*)d_in[8];
    const float* bv      = (const float*)d_in[9];
    const float* Wo      = (const float*)d_in[10];
    const float* bo      = (const float*)d_in[11];
    const float* gamma   = (const float*)d_in[12];
    const float* beta    = (const float*)d_in[13];
    const float* gate    = (const float*)d_in[14];
    const float* bscale  = (const float*)d_in[15];

    char* w = (char*)d_ws;
    bf16_t* qb     = (bf16_t*)(w);                  // 4 MB bf16 [4096,512]
    bf16_t* kb     = (bf16_t*)(w + (4u  << 20));    // 4 MB
    bf16_t* vb     = (bf16_t*)(w + (8u  << 20));    // 4 MB
    bf16_t* Wb     = (bf16_t*)(w + (12u << 20));    // 2 MB concat Wq,Wk,Wv,Wo bf16
    bf16_t* Qp     = (bf16_t*)(w + (14u << 20));    // 4 MB [B,H,TA,HD]
    bf16_t* Kp     = (bf16_t*)(w + (18u << 20));    // 4 MB [B,H,TV,HD]
    bf16_t* Vt     = (bf16_t*)(w + (22u << 20));    // 4 MB [B,H,HD,TV]
    bf16_t* ctx    = (bf16_t*)(w + (26u << 20));    // 4 MB [B,TA,D]
    hf16_t* bias_t = (hf16_t*)(w + (30u << 20));    // 8 MB tiled fp16
    bf16_t* Opart  = (bf16_t*)(w + (38u << 20));    // 8 MB [ks=2][512][256][16] bf16
    float*  mpart  = (float*) (w + (46u << 20));    // 256 KB [2][512][64]
    float*  lpart  = (float*) (w + (47u << 20));    // 256 KB
    bf16_t* op     = (bf16_t*)(w);                  // 4 MB bf16, overlays qb (dead after gemm_qkv)

    prep_all<<<4608, 256, 0, stream>>>(guide, bias_t, q, k, v, Wq, Wk, Wv, Wo, qb, kb, vb, Wb);
    gemm_qkv<<<dim3(32, 4, 3), 256, 0, stream>>>(qb, kb, vb, Wb, bq, bk, bv, Qp, Kp, Vt);
    attn_kernel<<<dim3(32, 16, 2), 256, 0, stream>>>(Qp, Kp, Vt, bias_t, bscale, Opart, mpart, lpart);
    attn_combine<<<dim3(32, 16), 256, 0, stream>>>(Opart, mpart, lpart, ctx);
    gemm_out<<<dim3(32, 4), 256, 0, stream>>>(ctx, Wb + ((size_t)3 << 18), bo, op);
    ln_kernel<<<4096, 256, 0, stream>>>(q, op, gamma, beta, gate, (float*)d_out);
}

// Round 9
// 181.860 us; speedup vs baseline: 1.0048x; 1.0048x over previous
//
#include <hip/hip_runtime.h>
#include <hip/hip_bf16.h>
#include <math.h>

// GuidedAttention: B=4, TA=TV=1024, D=512, H=8, HD=64. All I/O fp32.
// bf16 MFMA internally, fp32 accumulate.
// Round 9: S^T attention (mfma operand swap) -> register softmax (per-lane m/l,
// 2 shuffles) + P stays in registers feeding 16x16x16 PV MFMAs (no Plds
// round-trip, LDS 46->37 KB, 4 blocks/CU). bias_t repacked to match.
typedef __bf16 bf16_t;
typedef _Float16 hf16_t;
typedef bf16_t bf16x8 __attribute__((ext_vector_type(8)));
typedef bf16_t bf16x4 __attribute__((ext_vector_type(4)));
typedef hf16_t hf16x8 __attribute__((ext_vector_type(8)));
typedef float f32x4 __attribute__((ext_vector_type(4)));
typedef short s16x4 __attribute__((ext_vector_type(4)));

#define B_  4
#define TA_ 1024
#define TV_ 1024
#define D_  512
#define H_  8
#define HD_ 64
#define SCALE_ 0.125f

// async global->LDS copy, 16 B per lane (global_load_lds_dwordx4).
__device__ inline void g2l16(const void* g, void* l) {
    __builtin_amdgcn_global_load_lds(
        (const __attribute__((address_space(1))) void*)g,
        (__attribute__((address_space(3))) void*)l, 16, 0, 0);
}

__device__ inline f32x4 mfma16_bf16(bf16x4 a, bf16x4 b, f32x4 c) {
    return __builtin_amdgcn_mfma_f32_16x16x16bf16_1k(
        __builtin_bit_cast(s16x4, a), __builtin_bit_cast(s16x4, b), c, 0, 0, 0);
}

// ---- fused prep: blocks [0,1024) = bias tiling; [1024, 4608) = fp32->bf16 cvt.
// bias_t[b][kt][q64][tid][ct*4+r] = log(G[b][q64*64+wave*16+l16][kt*64+ct*16+quad*4+r]+1e-8)
// (S^T fragment order: q = l16, k = 16ct+4quad+r)
__global__ __launch_bounds__(256) void prep_all(
    const float* __restrict__ G, hf16_t* __restrict__ bias_t,
    const float* __restrict__ q, const float* __restrict__ k, const float* __restrict__ v,
    const float* __restrict__ Wq, const float* __restrict__ Wk,
    const float* __restrict__ Wv, const float* __restrict__ Wo,
    bf16_t* __restrict__ qb, bf16_t* __restrict__ kb, bf16_t* __restrict__ vb,
    bf16_t* __restrict__ Wb)
{
    const int tid = threadIdx.x;
    if (blockIdx.x < 1024) {
        __shared__ float Gt[64][68];
        const int kt = blockIdx.x & 15, q64 = (blockIdx.x >> 4) & 15, b = blockIdx.x >> 8;
        const int row = tid >> 4, col4 = (tid & 15) * 4;
        #pragma unroll
        for (int it = 0; it < 4; ++it) {
            int r = it * 16 + row;
            f32x4 g = *(const f32x4*)(G + ((size_t)(b * TA_ + q64 * 64 + r)) * TV_ + kt * 64 + col4);
            *(f32x4*)&Gt[r][col4] = g;
        }
        __syncthreads();
        const int lane = tid & 63, wave = tid >> 6, quad = lane >> 4, l16 = lane & 15;
        hf16x8 lo, hi;
        #pragma unroll
        for (int ct = 0; ct < 4; ++ct) {
            #pragma unroll
            for (int r = 0; r < 4; ++r) {
                float gv = Gt[wave * 16 + l16][ct * 16 + quad * 4 + r];
                float lb = __logf(gv + 1e-8f);
                int idx = ct * 4 + r;
                if (idx < 8) lo[idx] = (hf16_t)lb; else hi[idx - 8] = (hf16_t)lb;
            }
        }
        size_t doff = ((((size_t)b * 16 + kt) * 16 + q64) * 256 + tid) * 16;
        *(hf16x8*)(bias_t + doff) = lo;
        *(hf16x8*)(bias_t + doff + 8) = hi;
    } else {
        const size_t i = ((size_t)(blockIdx.x - 1024) * 256 + tid) * 8;
        const float* src; bf16_t* dst; size_t off;
        const size_t M2 = (size_t)1 << 21;
        if (i < M2)          { src = q; dst = qb; off = i; }
        else if (i < 2 * M2) { src = k; dst = kb; off = i - M2; }
        else if (i < 3 * M2) { src = v; dst = vb; off = i - 2 * M2; }
        else {
            size_t j = i - 3 * M2;
            int wsel = (int)(j >> 18); off = j & 262143;
            src = (wsel == 0) ? Wq : (wsel == 1) ? Wk : (wsel == 2) ? Wv : Wo;
            dst = Wb + ((size_t)wsel << 18);
        }
        f32x4 a = *(const f32x4*)(src + off), c = *(const f32x4*)(src + off + 4);
        bf16x8 r;
        #pragma unroll
        for (int t = 0; t < 4; ++t) { r[t] = (bf16_t)a[t]; r[t + 4] = (bf16_t)c[t]; }
        *(bf16x8*)(dst + off) = r;
    }
}

// ---- 128x128 LDS-staged GEMM main loop (m97 structure).
__device__ inline void gemm128_core(
    const bf16_t* __restrict__ X, const bf16_t* __restrict__ W,
    int mbase, int nbase, bf16_t (*__restrict__ Asm)[128 * 32],
    bf16_t (*__restrict__ Bsm)[128 * 32], f32x4 acc[4][4])
{
    const int tid  = threadIdx.x;
    const int wave = tid >> 6, lane = tid & 63;
    const int quad = lane >> 4, l16 = lane & 15;
    const int wm = wave & 1, wn = wave >> 1;
    const int srow = lane >> 2;           // staging: 16 rows x 4 chunks of 16B
    const int scol = (lane & 3) * 8;      // elements

    auto stage = [&](int kt, int buf) {
        const int k0 = kt * 32;
        #pragma unroll
        for (int i = 0; i < 2; ++i) {
            const int row = wave * 32 + i * 16;
            g2l16(X + (size_t)(mbase + row + srow) * D_ + k0 + scol,
                  &Asm[buf][row * 32] + (size_t)lane * 8);
            g2l16(W + (size_t)(nbase + row + srow) * D_ + k0 + scol,
                  &Bsm[buf][row * 32] + (size_t)lane * 8);
        }
    };

    stage(0, 0);
    __syncthreads();
    for (int kt = 0; kt < 16; ++kt) {
        const int buf = kt & 1;
        if (kt < 15) stage(kt + 1, buf ^ 1);
        bf16x8 af[4], bf_[4];
        #pragma unroll
        for (int t = 0; t < 4; ++t) {
            af[t]  = *(const bf16x8*)&Asm[buf][(wm * 64 + t * 16 + l16) * 32 + quad * 8];
            bf_[t] = *(const bf16x8*)&Bsm[buf][(wn * 64 + t * 16 + l16) * 32 + quad * 8];
        }
        #pragma unroll
        for (int mt = 0; mt < 4; ++mt) {
            #pragma unroll
            for (int nt = 0; nt < 4; ++nt)
                acc[mt][nt] = __builtin_amdgcn_mfma_f32_16x16x32_bf16(af[mt], bf_[nt], acc[mt][nt], 0, 0, 0);
        }
        __syncthreads();
    }
}

// Fused QKV projection, 128x128 tiles. z=0: qb->Qp [B,H,T,HD]; z=1: kb->Kp; z=2: vb->Vt [B,H,HD,T]
__global__ __launch_bounds__(256) void gemm_qkv(
    const bf16_t* __restrict__ qb, const bf16_t* __restrict__ kb, const bf16_t* __restrict__ vb,
    const bf16_t* __restrict__ Wb,
    const float* __restrict__ bq, const float* __restrict__ bk, const float* __restrict__ bv,
    bf16_t* __restrict__ Qp, bf16_t* __restrict__ Kp, bf16_t* __restrict__ Vt)
{
    __shared__ bf16_t Asm[2][128 * 32];
    __shared__ bf16_t Bsm[2][128 * 32];

    const int tid  = threadIdx.x;
    const int wave = tid >> 6, lane = tid & 63;
    const int quad = lane >> 4, l16 = lane & 15;
    const int wm = wave & 1, wn = wave >> 1;
    const int mbase = blockIdx.x * 128, nbase = blockIdx.y * 128;
    const int z = blockIdx.z;

    const bf16_t* X   = (z == 0) ? qb : (z == 1) ? kb : vb;
    const float* bias = (z == 0) ? bq : (z == 1) ? bk : bv;
    const bf16_t* W   = Wb + ((size_t)z << 18);

    f32x4 acc[4][4] = {};
    gemm128_core(X, W, mbase, nbase, Asm, Bsm, acc);

    bf16_t* out = (z == 0) ? Qp : (z == 1) ? Kp : Vt;
    #pragma unroll
    for (int mt = 0; mt < 4; ++mt) {
        #pragma unroll
        for (int nt = 0; nt < 4; ++nt) {
            #pragma unroll
            for (int r = 0; r < 4; ++r) {
                int m = mbase + wm * 64 + mt * 16 + quad * 4 + r;  // token index
                int n = nbase + wn * 64 + nt * 16 + l16;           // output channel
                float val = acc[mt][nt][r] + bias[n];
                int b = m >> 10, t = m & 1023, h = n >> 6, hd = n & 63;
                if (z != 2)
                    out[(((size_t)(b * H_ + h) * TA_) + t) * HD_ + hd] = (bf16_t)val;
                else
                    out[((size_t)(b * H_ + h) * HD_ + hd) * TV_ + t] = (bf16_t)val;
            }
        }
    }
}

// Out projection, 128x128 tiles: ctx [4096,512] bf16 @ Wo^T + bo -> bf16 [4096,512]
__global__ __launch_bounds__(256) void gemm_out(
    const bf16_t* __restrict__ ctx, const bf16_t* __restrict__ Wob,
    const float* __restrict__ bo, bf16_t* __restrict__ op)
{
    __shared__ bf16_t Asm[2][128 * 32];
    __shared__ bf16_t Bsm[2][128 * 32];

    const int tid  = threadIdx.x;
    const int wave = tid >> 6, lane = tid & 63;
    const int quad = lane >> 4, l16 = lane & 15;
    const int wm = wave & 1, wn = wave >> 1;
    const int mbase = blockIdx.x * 128, nbase = blockIdx.y * 128;

    f32x4 acc[4][4] = {};
    gemm128_core(ctx, Wob, mbase, nbase, Asm, Bsm, acc);

    #pragma unroll
    for (int mt = 0; mt < 4; ++mt) {
        #pragma unroll
        for (int nt = 0; nt < 4; ++nt) {
            #pragma unroll
            for (int r = 0; r < 4; ++r) {
                int m = mbase + wm * 64 + mt * 16 + quad * 4 + r;
                int n = nbase + wn * 64 + nt * 16 + l16;
                op[(size_t)m * D_ + n] = (bf16_t)(acc[mt][nt][r] + bo[n]);
            }
        }
    }
}

// ---- Flash attention, split-K, S^T formulation.
// Qp,Kp: [B,H,T,HD] bf16; Vt: [B,H,HD,TV] bf16; bias_t: tiled fp16 (S^T order).
// Grid (bh=32, q64=16, ks=2); block = 4 waves; wave owns 16 q-rows (q = l16).
// S^T frag: q=l16, k=16ct+4quad+r -> softmax is per-lane regs + xor16/32 shuffles;
// P feeds 16x16x16 PV MFMAs directly from registers (no LDS round-trip).
__global__ __launch_bounds__(256) void attn_kernel(
    const bf16_t* __restrict__ Qp, const bf16_t* __restrict__ Kp,
    const bf16_t* __restrict__ Vt, const hf16_t* __restrict__ bias_t,
    const float* __restrict__ bias_scale,
    bf16_t* __restrict__ Opart, float* __restrict__ mpart, float* __restrict__ lpart)
{
    __shared__ bf16_t Ksm[2][64][72];   // [buf][krow][hd]
    __shared__ bf16_t Vsm[2][64][72];   // [buf][hd][kcol]

    const int tid  = threadIdx.x;
    const int wave = tid >> 6, lane = tid & 63;
    const int quad = lane >> 4, l16 = lane & 15;
    const int bh = blockIdx.x, b = bh >> 3;
    const int q64 = blockIdx.y;
    const int z = blockIdx.z;        // split-K half
    const int t0 = z * 8;            // first k-tile
    const int qbase = q64 * 64 + wave * 16;
    const int rsub = lane >> 3, csub = lane & 7;   // staging: 8 rows x 8 chunks of 16B
    // shuffle source lane for O-row r redistribution: same 16-row, l16' = quad*4+r
    const int shsrc = (lane & 48) | ((lane >> 2) & 12);

    const float sp = log1pf(__expf(bias_scale[0]));  // softplus(bias_scale)

    // Q fragments (used as MFMA B operand: n=l16=q, k=hd=quad*8+j)
    bf16x8 aq[2];
    #pragma unroll
    for (int s = 0; s < 2; ++s)
        aq[s] = *(const bf16x8*)(Qp + ((size_t)bh * TA_ + qbase + l16) * HD_ + s * 32 + quad * 8);

    f32x4 o[4] = {};
    float m_ = -1e30f, l_ = 0.f;   // per-lane: q-row l16

    auto issue_kv = [&](int kt, bf16x8 kr[2], bf16x8 vr[2]) {
        const int kbase = kt * 64;
        #pragma unroll
        for (int i = 0; i < 2; ++i) {
            int row = wave * 16 + i * 8 + rsub;
            kr[i] = *(const bf16x8*)(Kp + ((size_t)bh * TV_ + kbase + row) * HD_ + csub * 8);
            vr[i] = *(const bf16x8*)(Vt + ((size_t)bh * HD_ + row) * TV_ + kbase + csub * 8);
        }
    };
    auto write_kv = [&](int buf, bf16x8 kr[2], bf16x8 vr[2]) {
        #pragma unroll
        for (int i = 0; i < 2; ++i) {
            int row = wave * 16 + i * 8 + rsub;
            *(bf16x8*)&Ksm[buf][row][csub * 8] = kr[i];
            *(bf16x8*)&Vsm[buf][row][csub * 8] = vr[i];
        }
    };

    const hf16_t* bias_base = bias_t + (((size_t)b * 16 * 16 + q64) * 256 + tid) * 16;
    auto bias_ld = [&](int kt, hf16x8& lo, hf16x8& hi) {
        const hf16_t* bp = bias_base + (size_t)kt * 65536;  // kt stride = 16*256*16
        lo = *(const hf16x8*)bp;
        hi = *(const hf16x8*)(bp + 8);
    };
    // static ring slots: slot0 = even local tiles, slot1 = odd
    hf16x8 b0lo, b0hi, b1lo, b1hi;
    bias_ld(t0, b0lo, b0hi);
    bias_ld(t0 + 1, b1lo, b1hi);

    {
        bf16x8 kr[2], vr[2];
        issue_kv(t0, kr, vr);
        write_kv(0, kr, vr);
    }
    __syncthreads();

    // one K-tile; lk = local tile index (0..7), buf literal, static ring slot refs
    auto tile_body = [&](int lk, int buf, hf16x8& slo, hf16x8& shi) {
        const int kt = t0 + lk;
        bf16x8 krn[2], vrn[2];
        if (lk < 7) issue_kv(kt + 1, krn, vrn);
        hf16x8 clo = slo, chi = shi;
        if (lk < 6) bias_ld(kt + 2, slo, shi);

        // S^T = K . Q^T  (A = K frag from Ksm, B = Q frag)
        f32x4 st[4];
        #pragma unroll
        for (int ct = 0; ct < 4; ++ct) {
            f32x4 acc = {};
            #pragma unroll
            for (int s = 0; s < 2; ++s) {
                bf16x8 bk = *(const bf16x8*)&Ksm[buf][ct * 16 + l16][s * 32 + quad * 8];
                acc = __builtin_amdgcn_mfma_f32_16x16x32_bf16(bk, aq[s], acc, 0, 0, 0);
            }
            st[ct] = acc;
        }
        // bias + per-lane softmax over 16 regs (k = 16ct+4quad+r for q = l16)
        float sv[4][4], mx = -1e30f;
        #pragma unroll
        for (int ct = 0; ct < 4; ++ct) {
            #pragma unroll
            for (int r = 0; r < 4; ++r) {
                int idx = ct * 4 + r;
                float lb = (idx < 8) ? (float)clo[idx] : (float)chi[idx - 8];
                float val = fmaf(lb, sp, st[ct][r] * SCALE_);
                sv[ct][r] = val;
                mx = fmaxf(mx, val);
            }
        }
        mx = fmaxf(mx, __shfl_xor(mx, 16, 64));
        mx = fmaxf(mx, __shfl_xor(mx, 32, 64));
        float mn = fmaxf(m_, mx);
        float alpha = __expf(m_ - mn);
        m_ = mn;
        float ls = 0.f;
        #pragma unroll
        for (int ct = 0; ct < 4; ++ct) {
            #pragma unroll
            for (int r = 0; r < 4; ++r) {
                float p = __expf(sv[ct][r] - mn);
                sv[ct][r] = p;
                ls += p;
            }
        }
        ls += __shfl_xor(ls, 16, 64);
        ls += __shfl_xor(ls, 32, 64);
        l_ = l_ * alpha + ls;
        // redistribute alpha to O's C-frag rows (q = quad*4+r) and rescale O
        #pragma unroll
        for (int r = 0; r < 4; ++r) {
            float af = __shfl(alpha, shsrc | r, 64);
            #pragma unroll
            for (int dt = 0; dt < 4; ++dt) o[dt][r] *= af;
        }
        // O += P.V via 16x16x16 MFMA: A = P chunk (regs!), B = V chunk (b64 from Vsm)
        #pragma unroll
        for (int ct = 0; ct < 4; ++ct) {
            bf16x4 ap;
            #pragma unroll
            for (int r = 0; r < 4; ++r) ap[r] = (bf16_t)sv[ct][r];
            #pragma unroll
            for (int dt = 0; dt < 4; ++dt) {
                bf16x4 bv = *(const bf16x4*)&Vsm[buf][dt * 16 + l16][ct * 16 + quad * 4];
                o[dt] = mfma16_bf16(ap, bv, o[dt]);
            }
        }
        if (lk < 7) write_kv(buf ^ 1, krn, vrn);
        __syncthreads();
    };

    #pragma unroll 1
    for (int kk = 0; kk < 8; kk += 2) {
        tile_body(kk,     0, b0lo, b0hi);
        tile_body(kk + 1, 1, b1lo, b1hi);
    }

    // store unnormalized partial O (bf16, C-frag-linear: coalesced 2x16B) + m/l
    const size_t blk = (size_t)bh * 16 + q64;
    bf16x8 plo, phi;
    #pragma unroll
    for (int dt = 0; dt < 4; ++dt) {
        #pragma unroll
        for (int r = 0; r < 4; ++r) {
            int idx = dt * 4 + r;
            if (idx < 8) plo[idx] = (bf16_t)o[dt][r]; else phi[idx - 8] = (bf16_t)o[dt][r];
        }
    }
    size_t poff = (((size_t)z * 512 + blk) * 256 + tid) * 16;
    *(bf16x8*)(Opart + poff) = plo;
    *(bf16x8*)(Opart + poff + 8) = phi;
    if (quad == 0) {
        int row = wave * 16 + l16;     // per-lane m/l is for q-row l16
        mpart[((size_t)z * 512 + blk) * 64 + row] = m_;
        lpart[((size_t)z * 512 + blk) * 64 + row] = l_;
    }
}

// ---- combine the two split-K halves -> ctx [B,TA,D] bf16
__global__ __launch_bounds__(256) void attn_combine(
    const bf16_t* __restrict__ Opart, const float* __restrict__ mpart,
    const float* __restrict__ lpart, bf16_t* __restrict__ ctx)
{
    const int tid  = threadIdx.x;
    const int wave = tid >> 6, lane = tid & 63;
    const int quad = lane >> 4, l16 = lane & 15;
    const int bh = blockIdx.x, b = bh >> 3, h = bh & 7;
    const int q64 = blockIdx.y;
    const size_t blk = (size_t)bh * 16 + q64;

    size_t p0 = (blk * 256 + tid) * 16;
    size_t p1 = (((size_t)512 + blk) * 256 + tid) * 16;
    bf16x8 a0 = *(const bf16x8*)(Opart + p0), a1 = *(const bf16x8*)(Opart + p0 + 8);
    bf16x8 c0 = *(const bf16x8*)(Opart + p1), c1 = *(const bf16x8*)(Opart + p1 + 8);

    float s0[4], s1[4];
    #pragma unroll
    for (int r = 0; r < 4; ++r) {
        int row = wave * 16 + quad * 4 + r;
        float m0 = mpart[blk * 64 + row], m1 = mpart[(512 + blk) * 64 + row];
        float l0 = lpart[blk * 64 + row], l1 = lpart[(512 + blk) * 64 + row];
        float mm = fmaxf(m0, m1);
        float e0 = __expf(m0 - mm), e1 = __expf(m1 - mm);
        float L = l0 * e0 + l1 * e1;
        s0[r] = e0 / L; s1[r] = e1 / L;
    }
    #pragma unroll
    for (int dt = 0; dt < 4; ++dt) {
        #pragma unroll
        for (int r = 0; r < 4; ++r) {
            int idx = dt * 4 + r;
            float v0 = (idx < 8) ? (float)a0[idx] : (float)a1[idx - 8];
            float v1 = (idx < 8) ? (float)c0[idx] : (float)c1[idx - 8];
            float v = v0 * s0[r] + v1 * s1[r];
            int qrow = q64 * 64 + wave * 16 + quad * 4 + r;
            ctx[((size_t)b * TA_ + qrow) * D_ + h * HD_ + dt * 16 + l16] = (bf16_t)v;
        }
    }
}

// y = LayerNorm(q + sigmoid(gate)*out) * gamma + beta, one block per row of 512
__global__ __launch_bounds__(256) void ln_kernel(
    const float* __restrict__ q, const bf16_t* __restrict__ outp,
    const float* __restrict__ gamma, const float* __restrict__ beta,
    const float* __restrict__ gate, float* __restrict__ y)
{
    const int row = blockIdx.x, tid = threadIdx.x;
    const float sg = 1.f / (1.f + __expf(-gate[0]));
    const size_t base = (size_t)row * D_;
    float x0 = q[base + tid]       + sg * (float)outp[base + tid];
    float x1 = q[base + tid + 256] + sg * (float)outp[base + tid + 256];
    float s = x0 + x1, sq = x0 * x0 + x1 * x1;
    #pragma unroll
    for (int off = 1; off < 64; off <<= 1) {
        s  += __shfl_xor(s,  off, 64);
        sq += __shfl_xor(sq, off, 64);
    }
    __shared__ float ss[4], sqq[4];
    if ((tid & 63) == 0) { ss[tid >> 6] = s; sqq[tid >> 6] = sq; }
    __syncthreads();
    s  = ss[0] + ss[1] + ss[2] + ss[3];
    sq = sqq[0] + sqq[1] + sqq[2] + sqq[3];
    const float mu = s * (1.f / D_);
    const float var = sq * (1.f / D_) - mu * mu;
    const float rstd = rsqrtf(var + 1e-5f);
    y[base + tid]       = (x0 - mu) * rstd * gamma[tid] + beta[tid];
    y[base + tid + 256] = (x1 - mu) * rstd * gamma[tid + 256] + beta[tid + 256];
}

extern "C" void kernel_launch(void* const* d_in, const int* in_sizes, int n_in,
                              void* d_out, int out_size, void* d_ws, size_t ws_size,
                              hipStream_t stream) {
    const float* q       = (const float*)d_in[0];
    const float* k       = (const float*)d_in[1];
    const float* v       = (const float*)d_in[2];
    const float* guide   = (const float*)d_in[3];
    const float* Wq      = (const float*)d_in[4];
    const float* bq      = (const float*)d_in[5];
    const float* Wk      = (const float*)d_in[6];
    const float* bk      = (const float*)d_in[7];
    const float* Wv      = (const float*)d_in[8];
    const float* bv      = (const float*)d_in[9];
    const float* Wo      = (const float*)d_in[10];
    const float* bo      = (const float*)d_in[11];
    const float* gamma   = (const float*)d_in[12];
    const float* beta    = (const float*)d_in[13];
    const float* gate    = (const float*)d_in[14];
    const float* bscale  = (const float*)d_in[15];

    char* w = (char*)d_ws;
    bf16_t* qb     = (bf16_t*)(w);                  // 4 MB bf16 [4096,512]
    bf16_t* kb     = (bf16_t*)(w + (4u  << 20));    // 4 MB
    bf16_t* vb     = (bf16_t*)(w + (8u  << 20));    // 4 MB
    bf16_t* Wb     = (bf16_t*)(w + (12u << 20));    // 2 MB concat Wq,Wk,Wv,Wo bf16
    bf16_t* Qp     = (bf16_t*)(w + (14u << 20));    // 4 MB [B,H,TA,HD]
    bf16_t* Kp     = (bf16_t*)(w + (18u << 20));    // 4 MB [B,H,TV,HD]
    bf16_t* Vt     = (bf16_t*)(w + (22u << 20));    // 4 MB [B,H,HD,TV]
    bf16_t* ctx    = (bf16_t*)(w + (26u << 20));    // 4 MB [B,TA,D]
    hf16_t* bias_t = (hf16_t*)(w + (30u << 20));    // 8 MB tiled fp16
    bf16_t* Opart  = (bf16_t*)(w + (38u << 20));    // 8 MB [ks=2][512][256][16] bf16
    float*  mpart  = (float*) (w + (46u << 20));    // 256 KB [2][512][64]
    float*  lpart  = (float*) (w + (47u << 20));    // 256 KB
    bf16_t* op     = (bf16_t*)(w);                  // 4 MB bf16, overlays qb (dead after gemm_qkv)

    prep_all<<<4608, 256, 0, stream>>>(guide, bias_t, q, k, v, Wq, Wk, Wv, Wo, qb, kb, vb, Wb);
    gemm_qkv<<<dim3(32, 4, 3), 256, 0, stream>>>(qb, kb, vb, Wb, bq, bk, bv, Qp, Kp, Vt);
    attn_kernel<<<dim3(32, 16, 2), 256, 0, stream>>>(Qp, Kp, Vt, bias_t, bscale, Opart, mpart, lpart);
    attn_combine<<<dim3(32, 16), 256, 0, stream>>>(Opart, mpart, lpart, ctx);
    gemm_out<<<dim3(32, 4), 256, 0, stream>>>(ctx, Wb + ((size_t)3 << 18), bo, op);
    ln_kernel<<<4096, 256, 0, stream>>>(q, op, gamma, beta, gate, (float*)d_out);
}

// Round 10
// 178.183 us; speedup vs baseline: 1.0256x; 1.0206x over previous
//
#include <hip/hip_runtime.h>
#include <hip/hip_bf16.h>
#include <math.h>

// GuidedAttention: B=4, TA=TV=1024, D=512, H=8, HD=64. All I/O fp32.
// bf16 MFMA internally, fp32 accumulate.
// Round 10: in-block split-K attention (512 thr, 8 waves: waves 0-3 = k-tiles
// 0-7, waves 4-7 = k-tiles 8-15; fp32 combine through reused LDS) -> deletes
// the attn_combine dispatch + 24 MB Opart traffic. Else unchanged from round 9.
typedef __bf16 bf16_t;
typedef _Float16 hf16_t;
typedef bf16_t bf16x8 __attribute__((ext_vector_type(8)));
typedef bf16_t bf16x4 __attribute__((ext_vector_type(4)));
typedef hf16_t hf16x8 __attribute__((ext_vector_type(8)));
typedef float f32x4 __attribute__((ext_vector_type(4)));
typedef short s16x4 __attribute__((ext_vector_type(4)));

#define B_  4
#define TA_ 1024
#define TV_ 1024
#define D_  512
#define H_  8
#define HD_ 64
#define SCALE_ 0.125f

// async global->LDS copy, 16 B per lane (global_load_lds_dwordx4).
__device__ inline void g2l16(const void* g, void* l) {
    __builtin_amdgcn_global_load_lds(
        (const __attribute__((address_space(1))) void*)g,
        (__attribute__((address_space(3))) void*)l, 16, 0, 0);
}

__device__ inline f32x4 mfma16_bf16(bf16x4 a, bf16x4 b, f32x4 c) {
    return __builtin_amdgcn_mfma_f32_16x16x16bf16_1k(
        __builtin_bit_cast(s16x4, a), __builtin_bit_cast(s16x4, b), c, 0, 0, 0);
}

// ---- fused prep: blocks [0,1024) = bias tiling; [1024, 4608) = fp32->bf16 cvt.
// bias_t[b][kt][q64][tid][ct*4+r] = log(G[b][q64*64+wave*16+l16][kt*64+ct*16+quad*4+r]+1e-8)
// (S^T fragment order: q = l16, k = 16ct+4quad+r)
__global__ __launch_bounds__(256) void prep_all(
    const float* __restrict__ G, hf16_t* __restrict__ bias_t,
    const float* __restrict__ q, const float* __restrict__ k, const float* __restrict__ v,
    const float* __restrict__ Wq, const float* __restrict__ Wk,
    const float* __restrict__ Wv, const float* __restrict__ Wo,
    bf16_t* __restrict__ qb, bf16_t* __restrict__ kb, bf16_t* __restrict__ vb,
    bf16_t* __restrict__ Wb)
{
    const int tid = threadIdx.x;
    if (blockIdx.x < 1024) {
        __shared__ float Gt[64][68];
        const int kt = blockIdx.x & 15, q64 = (blockIdx.x >> 4) & 15, b = blockIdx.x >> 8;
        const int row = tid >> 4, col4 = (tid & 15) * 4;
        #pragma unroll
        for (int it = 0; it < 4; ++it) {
            int r = it * 16 + row;
            f32x4 g = *(const f32x4*)(G + ((size_t)(b * TA_ + q64 * 64 + r)) * TV_ + kt * 64 + col4);
            *(f32x4*)&Gt[r][col4] = g;
        }
        __syncthreads();
        const int lane = tid & 63, wave = tid >> 6, quad = lane >> 4, l16 = lane & 15;
        hf16x8 lo, hi;
        #pragma unroll
        for (int ct = 0; ct < 4; ++ct) {
            #pragma unroll
            for (int r = 0; r < 4; ++r) {
                float gv = Gt[wave * 16 + l16][ct * 16 + quad * 4 + r];
                float lb = __logf(gv + 1e-8f);
                int idx = ct * 4 + r;
                if (idx < 8) lo[idx] = (hf16_t)lb; else hi[idx - 8] = (hf16_t)lb;
            }
        }
        size_t doff = ((((size_t)b * 16 + kt) * 16 + q64) * 256 + tid) * 16;
        *(hf16x8*)(bias_t + doff) = lo;
        *(hf16x8*)(bias_t + doff + 8) = hi;
    } else {
        const size_t i = ((size_t)(blockIdx.x - 1024) * 256 + tid) * 8;
        const float* src; bf16_t* dst; size_t off;
        const size_t M2 = (size_t)1 << 21;
        if (i < M2)          { src = q; dst = qb; off = i; }
        else if (i < 2 * M2) { src = k; dst = kb; off = i - M2; }
        else if (i < 3 * M2) { src = v; dst = vb; off = i - 2 * M2; }
        else {
            size_t j = i - 3 * M2;
            int wsel = (int)(j >> 18); off = j & 262143;
            src = (wsel == 0) ? Wq : (wsel == 1) ? Wk : (wsel == 2) ? Wv : Wo;
            dst = Wb + ((size_t)wsel << 18);
        }
        f32x4 a = *(const f32x4*)(src + off), c = *(const f32x4*)(src + off + 4);
        bf16x8 r;
        #pragma unroll
        for (int t = 0; t < 4; ++t) { r[t] = (bf16_t)a[t]; r[t + 4] = (bf16_t)c[t]; }
        *(bf16x8*)(dst + off) = r;
    }
}

// ---- 128x128 LDS-staged GEMM main loop (m97 structure).
__device__ inline void gemm128_core(
    const bf16_t* __restrict__ X, const bf16_t* __restrict__ W,
    int mbase, int nbase, bf16_t (*__restrict__ Asm)[128 * 32],
    bf16_t (*__restrict__ Bsm)[128 * 32], f32x4 acc[4][4])
{
    const int tid  = threadIdx.x;
    const int wave = tid >> 6, lane = tid & 63;
    const int quad = lane >> 4, l16 = lane & 15;
    const int wm = wave & 1, wn = wave >> 1;
    const int srow = lane >> 2;           // staging: 16 rows x 4 chunks of 16B
    const int scol = (lane & 3) * 8;      // elements

    auto stage = [&](int kt, int buf) {
        const int k0 = kt * 32;
        #pragma unroll
        for (int i = 0; i < 2; ++i) {
            const int row = wave * 32 + i * 16;
            g2l16(X + (size_t)(mbase + row + srow) * D_ + k0 + scol,
                  &Asm[buf][row * 32] + (size_t)lane * 8);
            g2l16(W + (size_t)(nbase + row + srow) * D_ + k0 + scol,
                  &Bsm[buf][row * 32] + (size_t)lane * 8);
        }
    };

    stage(0, 0);
    __syncthreads();
    for (int kt = 0; kt < 16; ++kt) {
        const int buf = kt & 1;
        if (kt < 15) stage(kt + 1, buf ^ 1);
        bf16x8 af[4], bf_[4];
        #pragma unroll
        for (int t = 0; t < 4; ++t) {
            af[t]  = *(const bf16x8*)&Asm[buf][(wm * 64 + t * 16 + l16) * 32 + quad * 8];
            bf_[t] = *(const bf16x8*)&Bsm[buf][(wn * 64 + t * 16 + l16) * 32 + quad * 8];
        }
        #pragma unroll
        for (int mt = 0; mt < 4; ++mt) {
            #pragma unroll
            for (int nt = 0; nt < 4; ++nt)
                acc[mt][nt] = __builtin_amdgcn_mfma_f32_16x16x32_bf16(af[mt], bf_[nt], acc[mt][nt], 0, 0, 0);
        }
        __syncthreads();
    }
}

// Fused QKV projection, 128x128 tiles. z=0: qb->Qp [B,H,T,HD]; z=1: kb->Kp; z=2: vb->Vt [B,H,HD,T]
__global__ __launch_bounds__(256) void gemm_qkv(
    const bf16_t* __restrict__ qb, const bf16_t* __restrict__ kb, const bf16_t* __restrict__ vb,
    const bf16_t* __restrict__ Wb,
    const float* __restrict__ bq, const float* __restrict__ bk, const float* __restrict__ bv,
    bf16_t* __restrict__ Qp, bf16_t* __restrict__ Kp, bf16_t* __restrict__ Vt)
{
    __shared__ bf16_t Asm[2][128 * 32];
    __shared__ bf16_t Bsm[2][128 * 32];

    const int tid  = threadIdx.x;
    const int wave = tid >> 6, lane = tid & 63;
    const int quad = lane >> 4, l16 = lane & 15;
    const int wm = wave & 1, wn = wave >> 1;
    const int mbase = blockIdx.x * 128, nbase = blockIdx.y * 128;
    const int z = blockIdx.z;

    const bf16_t* X   = (z == 0) ? qb : (z == 1) ? kb : vb;
    const float* bias = (z == 0) ? bq : (z == 1) ? bk : bv;
    const bf16_t* W   = Wb + ((size_t)z << 18);

    f32x4 acc[4][4] = {};
    gemm128_core(X, W, mbase, nbase, Asm, Bsm, acc);

    bf16_t* out = (z == 0) ? Qp : (z == 1) ? Kp : Vt;
    #pragma unroll
    for (int mt = 0; mt < 4; ++mt) {
        #pragma unroll
        for (int nt = 0; nt < 4; ++nt) {
            #pragma unroll
            for (int r = 0; r < 4; ++r) {
                int m = mbase + wm * 64 + mt * 16 + quad * 4 + r;  // token index
                int n = nbase + wn * 64 + nt * 16 + l16;           // output channel
                float val = acc[mt][nt][r] + bias[n];
                int b = m >> 10, t = m & 1023, h = n >> 6, hd = n & 63;
                if (z != 2)
                    out[(((size_t)(b * H_ + h) * TA_) + t) * HD_ + hd] = (bf16_t)val;
                else
                    out[((size_t)(b * H_ + h) * HD_ + hd) * TV_ + t] = (bf16_t)val;
            }
        }
    }
}

// Out projection, 128x128 tiles: ctx [4096,512] bf16 @ Wo^T + bo -> bf16 [4096,512]
__global__ __launch_bounds__(256) void gemm_out(
    const bf16_t* __restrict__ ctx, const bf16_t* __restrict__ Wob,
    const float* __restrict__ bo, bf16_t* __restrict__ op)
{
    __shared__ bf16_t Asm[2][128 * 32];
    __shared__ bf16_t Bsm[2][128 * 32];

    const int tid  = threadIdx.x;
    const int wave = tid >> 6, lane = tid & 63;
    const int quad = lane >> 4, l16 = lane & 15;
    const int wm = wave & 1, wn = wave >> 1;
    const int mbase = blockIdx.x * 128, nbase = blockIdx.y * 128;

    f32x4 acc[4][4] = {};
    gemm128_core(ctx, Wob, mbase, nbase, Asm, Bsm, acc);

    #pragma unroll
    for (int mt = 0; mt < 4; ++mt) {
        #pragma unroll
        for (int nt = 0; nt < 4; ++nt) {
            #pragma unroll
            for (int r = 0; r < 4; ++r) {
                int m = mbase + wm * 64 + mt * 16 + quad * 4 + r;
                int n = nbase + wn * 64 + nt * 16 + l16;
                op[(size_t)m * D_ + n] = (bf16_t)(acc[mt][nt][r] + bo[n]);
            }
        }
    }
}

// ---- Flash attention, in-block split-K, S^T formulation. 512 threads.
// Waves 0-3: k-tiles 0-7; waves 4-7: k-tiles 8-15 (independent K/V LDS halves).
// S^T frag: q=l16, k=16ct+4quad+r -> per-lane softmax + register P -> 16x16x16 PV.
// Final: half-1 dumps fp32 O/m/l into dead Ksm space; half-0 merges, writes ctx.
__global__ __launch_bounds__(512, 4) void attn_kernel(
    const bf16_t* __restrict__ Qp, const bf16_t* __restrict__ Kp,
    const bf16_t* __restrict__ Vt, const hf16_t* __restrict__ bias_t,
    const float* __restrict__ bias_scale, bf16_t* __restrict__ ctx)
{
    __shared__ bf16_t Ksm[2][2][64][72];   // [half][buf][krow][hd]
    __shared__ bf16_t Vsm[2][2][64][72];   // [half][buf][hd][kcol]

    const int tid  = threadIdx.x;
    const int wave = tid >> 6, lane = tid & 63;
    const int half = wave >> 2, w4 = wave & 3;
    const int quad = lane >> 4, l16 = lane & 15;
    const int bh = blockIdx.x, b = bh >> 3, h = bh & 7;
    const int q64 = blockIdx.y;
    const int t0 = half * 8;            // first k-tile for this half
    const int qbase = q64 * 64 + w4 * 16;
    const int rsub = lane >> 3, csub = lane & 7;   // staging: 8 rows x 8 chunks of 16B
    // shuffle source lane: same quad, l16' = quad*4+r  (|r at use site)
    const int shsrc = (lane & 48) | ((lane >> 2) & 12);

    const float sp = log1pf(__expf(bias_scale[0]));  // softplus(bias_scale)

    // Q fragments (MFMA B operand: n=l16=q, k=hd)
    bf16x8 aq[2];
    #pragma unroll
    for (int s = 0; s < 2; ++s)
        aq[s] = *(const bf16x8*)(Qp + ((size_t)bh * TA_ + qbase + l16) * HD_ + s * 32 + quad * 8);

    f32x4 o[4] = {};
    float m_ = -1e30f, l_ = 0.f;   // per-lane: q-row l16

    auto issue_kv = [&](int kt, bf16x8 kr[2], bf16x8 vr[2]) {
        const int kbase = kt * 64;
        #pragma unroll
        for (int i = 0; i < 2; ++i) {
            int row = w4 * 16 + i * 8 + rsub;
            kr[i] = *(const bf16x8*)(Kp + ((size_t)bh * TV_ + kbase + row) * HD_ + csub * 8);
            vr[i] = *(const bf16x8*)(Vt + ((size_t)bh * HD_ + row) * TV_ + kbase + csub * 8);
        }
    };
    auto write_kv = [&](int buf, bf16x8 kr[2], bf16x8 vr[2]) {
        #pragma unroll
        for (int i = 0; i < 2; ++i) {
            int row = w4 * 16 + i * 8 + rsub;
            *(bf16x8*)&Ksm[half][buf][row][csub * 8] = kr[i];
            *(bf16x8*)&Vsm[half][buf][row][csub * 8] = vr[i];
        }
    };

    const int tidb = (w4 << 6) | lane;   // 0..255 packet index within (b,kt,q64)
    const hf16_t* bias_base = bias_t + (((size_t)b * 16 * 16 + q64) * 256 + tidb) * 16;
    auto bias_ld = [&](int kt, hf16x8& lo, hf16x8& hi) {
        const hf16_t* bp = bias_base + (size_t)kt * 65536;  // kt stride = 16*256*16
        lo = *(const hf16x8*)bp;
        hi = *(const hf16x8*)(bp + 8);
    };
    // static ring slots: slot0 = even local tiles, slot1 = odd
    hf16x8 b0lo, b0hi, b1lo, b1hi;
    bias_ld(t0, b0lo, b0hi);
    bias_ld(t0 + 1, b1lo, b1hi);

    {
        bf16x8 kr[2], vr[2];
        issue_kv(t0, kr, vr);
        write_kv(0, kr, vr);
    }
    __syncthreads();

    // one K-tile; lk = local tile index (0..7), buf literal, static ring slot refs
    auto tile_body = [&](int lk, int buf, hf16x8& slo, hf16x8& shi) {
        const int kt = t0 + lk;
        bf16x8 krn[2], vrn[2];
        if (lk < 7) issue_kv(kt + 1, krn, vrn);
        hf16x8 clo = slo, chi = shi;
        if (lk < 6) bias_ld(kt + 2, slo, shi);

        // S^T = K . Q^T  (A = K frag from Ksm, B = Q frag)
        f32x4 st[4];
        #pragma unroll
        for (int ct = 0; ct < 4; ++ct) {
            f32x4 acc = {};
            #pragma unroll
            for (int s = 0; s < 2; ++s) {
                bf16x8 bk = *(const bf16x8*)&Ksm[half][buf][ct * 16 + l16][s * 32 + quad * 8];
                acc = __builtin_amdgcn_mfma_f32_16x16x32_bf16(bk, aq[s], acc, 0, 0, 0);
            }
            st[ct] = acc;
        }
        // bias + per-lane softmax over 16 regs (k = 16ct+4quad+r for q = l16)
        float sv[4][4], mx = -1e30f;
        #pragma unroll
        for (int ct = 0; ct < 4; ++ct) {
            #pragma unroll
            for (int r = 0; r < 4; ++r) {
                int idx = ct * 4 + r;
                float lb = (idx < 8) ? (float)clo[idx] : (float)chi[idx - 8];
                float val = fmaf(lb, sp, st[ct][r] * SCALE_);
                sv[ct][r] = val;
                mx = fmaxf(mx, val);
            }
        }
        mx = fmaxf(mx, __shfl_xor(mx, 16, 64));
        mx = fmaxf(mx, __shfl_xor(mx, 32, 64));
        float mn = fmaxf(m_, mx);
        float alpha = __expf(m_ - mn);
        m_ = mn;
        float ls = 0.f;
        #pragma unroll
        for (int ct = 0; ct < 4; ++ct) {
            #pragma unroll
            for (int r = 0; r < 4; ++r) {
                float p = __expf(sv[ct][r] - mn);
                sv[ct][r] = p;
                ls += p;
            }
        }
        ls += __shfl_xor(ls, 16, 64);
        ls += __shfl_xor(ls, 32, 64);
        l_ = l_ * alpha + ls;
        // redistribute alpha to O's C-frag rows (q = quad*4+r) and rescale O
        #pragma unroll
        for (int r = 0; r < 4; ++r) {
            float af = __shfl(alpha, shsrc | r, 64);
            #pragma unroll
            for (int dt = 0; dt < 4; ++dt) o[dt][r] *= af;
        }
        // O += P.V via 16x16x16 MFMA: A = P chunk (regs), B = V chunk (b64 from Vsm)
        #pragma unroll
        for (int ct = 0; ct < 4; ++ct) {
            bf16x4 ap;
            #pragma unroll
            for (int r = 0; r < 4; ++r) ap[r] = (bf16_t)sv[ct][r];
            #pragma unroll
            for (int dt = 0; dt < 4; ++dt) {
                bf16x4 bv = *(const bf16x4*)&Vsm[half][buf][dt * 16 + l16][ct * 16 + quad * 4];
                o[dt] = mfma16_bf16(ap, bv, o[dt]);
            }
        }
        if (lk < 7) write_kv(buf ^ 1, krn, vrn);
        __syncthreads();
    };

    #pragma unroll 1
    for (int kk = 0; kk < 8; kk += 2) {
        tile_body(kk,     0, b0lo, b0hi);
        tile_body(kk + 1, 1, b1lo, b1hi);
    }

    // ---- in-block combine: Ksm is dead; reuse as fp32 buffer [256][18]
    float* cb = (float*)&Ksm[0][0][0][0];
    if (half == 1) {
        float* p = cb + (size_t)tidb * 18;
        #pragma unroll
        for (int dt = 0; dt < 4; ++dt) {
            #pragma unroll
            for (int r = 0; r < 4; ++r) p[dt * 4 + r] = o[dt][r];
        }
        p[16] = m_; p[17] = l_;
    }
    __syncthreads();
    if (half == 0) {
        const float* p = cb + (size_t)tidb * 18;   // half1's same-lane O
        float s0[4], s1[4];
        #pragma unroll
        for (int r = 0; r < 4; ++r) {
            float m0 = __shfl(m_, shsrc | r, 64);
            float l0 = __shfl(l_, shsrc | r, 64);
            const float* pr = cb + (size_t)((w4 << 6) | (shsrc | r)) * 18;
            float m1 = pr[16], l1 = pr[17];
            float mm = fmaxf(m0, m1);
            float e0 = __expf(m0 - mm), e1 = __expf(m1 - mm);
            float L = l0 * e0 + l1 * e1;
            s0[r] = e0 / L; s1[r] = e1 / L;
        }
        #pragma unroll
        for (int dt = 0; dt < 4; ++dt) {
            #pragma unroll
            for (int r = 0; r < 4; ++r) {
                float v = o[dt][r] * s0[r] + p[dt * 4 + r] * s1[r];
                int qrow = q64 * 64 + w4 * 16 + quad * 4 + r;
                ctx[((size_t)b * TA_ + qrow) * D_ + h * HD_ + dt * 16 + l16] = (bf16_t)v;
            }
        }
    }
}

// y = LayerNorm(q + sigmoid(gate)*out) * gamma + beta, one block per row of 512
__global__ __launch_bounds__(256) void ln_kernel(
    const float* __restrict__ q, const bf16_t* __restrict__ outp,
    const float* __restrict__ gamma, const float* __restrict__ beta,
    const float* __restrict__ gate, float* __restrict__ y)
{
    const int row = blockIdx.x, tid = threadIdx.x;
    const float sg = 1.f / (1.f + __expf(-gate[0]));
    const size_t base = (size_t)row * D_;
    float x0 = q[base + tid]       + sg * (float)outp[base + tid];
    float x1 = q[base + tid + 256] + sg * (float)outp[base + tid + 256];
    float s = x0 + x1, sq = x0 * x0 + x1 * x1;
    #pragma unroll
    for (int off = 1; off < 64; off <<= 1) {
        s  += __shfl_xor(s,  off, 64);
        sq += __shfl_xor(sq, off, 64);
    }
    __shared__ float ss[4], sqq[4];
    if ((tid & 63) == 0) { ss[tid >> 6] = s; sqq[tid >> 6] = sq; }
    __syncthreads();
    s  = ss[0] + ss[1] + ss[2] + ss[3];
    sq = sqq[0] + sqq[1] + sqq[2] + sqq[3];
    const float mu = s * (1.f / D_);
    const float var = sq * (1.f / D_) - mu * mu;
    const float rstd = rsqrtf(var + 1e-5f);
    y[base + tid]       = (x0 - mu) * rstd * gamma[tid] + beta[tid];
    y[base + tid + 256] = (x1 - mu) * rstd * gamma[tid + 256] + beta[tid + 256];
}

extern "C" void kernel_launch(void* const* d_in, const int* in_sizes, int n_in,
                              void* d_out, int out_size, void* d_ws, size_t ws_size,
                              hipStream_t stream) {
    const float* q       = (const float*)d_in[0];
    const float* k       = (const float*)d_in[1];
    const float* v       = (const float*)d_in[2];
    const float* guide   = (const float*)d_in[3];
    const float* Wq      = (const float*)d_in[4];
    const float* bq      = (const float*)d_in[5];
    const float* Wk      = (const float*)d_in[6];
    const float* bk      = (const float*)d_in[7];
    const float* Wv      = (const float*)d_in[8];
    const float* bv      = (const float*)d_in[9];
    const float* Wo      = (const float*)d_in[10];
    const float* bo      = (const float*)d_in[11];
    const float* gamma   = (const float*)d_in[12];
    const float* beta    = (const float*)d_in[13];
    const float* gate    = (const float*)d_in[14];
    const float* bscale  = (const float*)d_in[15];

    char* w = (char*)d_ws;
    bf16_t* qb     = (bf16_t*)(w);                  // 4 MB bf16 [4096,512]
    bf16_t* kb     = (bf16_t*)(w + (4u  << 20));    // 4 MB
    bf16_t* vb     = (bf16_t*)(w + (8u  << 20));    // 4 MB
    bf16_t* Wb     = (bf16_t*)(w + (12u << 20));    // 2 MB concat Wq,Wk,Wv,Wo bf16
    bf16_t* Qp     = (bf16_t*)(w + (14u << 20));    // 4 MB [B,H,TA,HD]
    bf16_t* Kp     = (bf16_t*)(w + (18u << 20));    // 4 MB [B,H,TV,HD]
    bf16_t* Vt     = (bf16_t*)(w + (22u << 20));    // 4 MB [B,H,HD,TV]
    bf16_t* ctx    = (bf16_t*)(w + (26u << 20));    // 4 MB [B,TA,D]
    hf16_t* bias_t = (hf16_t*)(w + (30u << 20));    // 8 MB tiled fp16
    bf16_t* op     = (bf16_t*)(w);                  // 4 MB bf16, overlays qb (dead after gemm_qkv)

    prep_all<<<4608, 256, 0, stream>>>(guide, bias_t, q, k, v, Wq, Wk, Wv, Wo, qb, kb, vb, Wb);
    gemm_qkv<<<dim3(32, 4, 3), 256, 0, stream>>>(qb, kb, vb, Wb, bq, bk, bv, Qp, Kp, Vt);
    attn_kernel<<<dim3(32, 16), 512, 0, stream>>>(Qp, Kp, Vt, bias_t, bscale, ctx);
    gemm_out<<<dim3(32, 4), 256, 0, stream>>>(ctx, Wb + ((size_t)3 << 18), bo, op);
    ln_kernel<<<4096, 256, 0, stream>>>(q, op, gamma, beta, gate, (float*)d_out);
}

// Round 11
// 177.480 us; speedup vs baseline: 1.0296x; 1.0040x over previous
//
#include <hip/hip_runtime.h>
#include <hip/hip_bf16.h>
#include <math.h>

// GuidedAttention: B=4, TA=TV=1024, D=512, H=8, HD=64. All I/O fp32.
// bf16 MFMA internally, fp32 accumulate.
// Round 11: gemm_out + ln fused into one full-row kernel (M=32 x N=512 blocks,
// 512 thr; LN in epilogue via shuffle+LDS row reduction; writes d_out fp32).
// Deletes ln dispatch + 12 MB op round-trip. attn/prep/qkv unchanged from r10.
typedef __bf16 bf16_t;
typedef _Float16 hf16_t;
typedef bf16_t bf16x8 __attribute__((ext_vector_type(8)));
typedef bf16_t bf16x4 __attribute__((ext_vector_type(4)));
typedef hf16_t hf16x8 __attribute__((ext_vector_type(8)));
typedef float f32x4 __attribute__((ext_vector_type(4)));
typedef short s16x4 __attribute__((ext_vector_type(4)));

#define B_  4
#define TA_ 1024
#define TV_ 1024
#define D_  512
#define H_  8
#define HD_ 64
#define SCALE_ 0.125f

// async global->LDS copy, 16 B per lane (global_load_lds_dwordx4).
__device__ inline void g2l16(const void* g, void* l) {
    __builtin_amdgcn_global_load_lds(
        (const __attribute__((address_space(1))) void*)g,
        (__attribute__((address_space(3))) void*)l, 16, 0, 0);
}

__device__ inline f32x4 mfma16_bf16(bf16x4 a, bf16x4 b, f32x4 c) {
    return __builtin_amdgcn_mfma_f32_16x16x16bf16_1k(
        __builtin_bit_cast(s16x4, a), __builtin_bit_cast(s16x4, b), c, 0, 0, 0);
}

// ---- fused prep: blocks [0,1024) = bias tiling; [1024, 4608) = fp32->bf16 cvt.
// bias_t[b][kt][q64][tid][ct*4+r] = log(G[b][q64*64+wave*16+l16][kt*64+ct*16+quad*4+r]+1e-8)
// (S^T fragment order: q = l16, k = 16ct+4quad+r)
__global__ __launch_bounds__(256) void prep_all(
    const float* __restrict__ G, hf16_t* __restrict__ bias_t,
    const float* __restrict__ q, const float* __restrict__ k, const float* __restrict__ v,
    const float* __restrict__ Wq, const float* __restrict__ Wk,
    const float* __restrict__ Wv, const float* __restrict__ Wo,
    bf16_t* __restrict__ qb, bf16_t* __restrict__ kb, bf16_t* __restrict__ vb,
    bf16_t* __restrict__ Wb)
{
    const int tid = threadIdx.x;
    if (blockIdx.x < 1024) {
        __shared__ float Gt[64][68];
        const int kt = blockIdx.x & 15, q64 = (blockIdx.x >> 4) & 15, b = blockIdx.x >> 8;
        const int row = tid >> 4, col4 = (tid & 15) * 4;
        #pragma unroll
        for (int it = 0; it < 4; ++it) {
            int r = it * 16 + row;
            f32x4 g = *(const f32x4*)(G + ((size_t)(b * TA_ + q64 * 64 + r)) * TV_ + kt * 64 + col4);
            *(f32x4*)&Gt[r][col4] = g;
        }
        __syncthreads();
        const int lane = tid & 63, wave = tid >> 6, quad = lane >> 4, l16 = lane & 15;
        hf16x8 lo, hi;
        #pragma unroll
        for (int ct = 0; ct < 4; ++ct) {
            #pragma unroll
            for (int r = 0; r < 4; ++r) {
                float gv = Gt[wave * 16 + l16][ct * 16 + quad * 4 + r];
                float lb = __logf(gv + 1e-8f);
                int idx = ct * 4 + r;
                if (idx < 8) lo[idx] = (hf16_t)lb; else hi[idx - 8] = (hf16_t)lb;
            }
        }
        size_t doff = ((((size_t)b * 16 + kt) * 16 + q64) * 256 + tid) * 16;
        *(hf16x8*)(bias_t + doff) = lo;
        *(hf16x8*)(bias_t + doff + 8) = hi;
    } else {
        const size_t i = ((size_t)(blockIdx.x - 1024) * 256 + tid) * 8;
        const float* src; bf16_t* dst; size_t off;
        const size_t M2 = (size_t)1 << 21;
        if (i < M2)          { src = q; dst = qb; off = i; }
        else if (i < 2 * M2) { src = k; dst = kb; off = i - M2; }
        else if (i < 3 * M2) { src = v; dst = vb; off = i - 2 * M2; }
        else {
            size_t j = i - 3 * M2;
            int wsel = (int)(j >> 18); off = j & 262143;
            src = (wsel == 0) ? Wq : (wsel == 1) ? Wk : (wsel == 2) ? Wv : Wo;
            dst = Wb + ((size_t)wsel << 18);
        }
        f32x4 a = *(const f32x4*)(src + off), c = *(const f32x4*)(src + off + 4);
        bf16x8 r;
        #pragma unroll
        for (int t = 0; t < 4; ++t) { r[t] = (bf16_t)a[t]; r[t + 4] = (bf16_t)c[t]; }
        *(bf16x8*)(dst + off) = r;
    }
}

// ---- 128x128 LDS-staged GEMM main loop (m97 structure).
__device__ inline void gemm128_core(
    const bf16_t* __restrict__ X, const bf16_t* __restrict__ W,
    int mbase, int nbase, bf16_t (*__restrict__ Asm)[128 * 32],
    bf16_t (*__restrict__ Bsm)[128 * 32], f32x4 acc[4][4])
{
    const int tid  = threadIdx.x;
    const int wave = tid >> 6, lane = tid & 63;
    const int quad = lane >> 4, l16 = lane & 15;
    const int wm = wave & 1, wn = wave >> 1;
    const int srow = lane >> 2;           // staging: 16 rows x 4 chunks of 16B
    const int scol = (lane & 3) * 8;      // elements

    auto stage = [&](int kt, int buf) {
        const int k0 = kt * 32;
        #pragma unroll
        for (int i = 0; i < 2; ++i) {
            const int row = wave * 32 + i * 16;
            g2l16(X + (size_t)(mbase + row + srow) * D_ + k0 + scol,
                  &Asm[buf][row * 32] + (size_t)lane * 8);
            g2l16(W + (size_t)(nbase + row + srow) * D_ + k0 + scol,
                  &Bsm[buf][row * 32] + (size_t)lane * 8);
        }
    };

    stage(0, 0);
    __syncthreads();
    for (int kt = 0; kt < 16; ++kt) {
        const int buf = kt & 1;
        if (kt < 15) stage(kt + 1, buf ^ 1);
        bf16x8 af[4], bf_[4];
        #pragma unroll
        for (int t = 0; t < 4; ++t) {
            af[t]  = *(const bf16x8*)&Asm[buf][(wm * 64 + t * 16 + l16) * 32 + quad * 8];
            bf_[t] = *(const bf16x8*)&Bsm[buf][(wn * 64 + t * 16 + l16) * 32 + quad * 8];
        }
        #pragma unroll
        for (int mt = 0; mt < 4; ++mt) {
            #pragma unroll
            for (int nt = 0; nt < 4; ++nt)
                acc[mt][nt] = __builtin_amdgcn_mfma_f32_16x16x32_bf16(af[mt], bf_[nt], acc[mt][nt], 0, 0, 0);
        }
        __syncthreads();
    }
}

// Fused QKV projection, 128x128 tiles. z=0: qb->Qp [B,H,T,HD]; z=1: kb->Kp; z=2: vb->Vt [B,H,HD,T]
__global__ __launch_bounds__(256) void gemm_qkv(
    const bf16_t* __restrict__ qb, const bf16_t* __restrict__ kb, const bf16_t* __restrict__ vb,
    const bf16_t* __restrict__ Wb,
    const float* __restrict__ bq, const float* __restrict__ bk, const float* __restrict__ bv,
    bf16_t* __restrict__ Qp, bf16_t* __restrict__ Kp, bf16_t* __restrict__ Vt)
{
    __shared__ bf16_t Asm[2][128 * 32];
    __shared__ bf16_t Bsm[2][128 * 32];

    const int tid  = threadIdx.x;
    const int wave = tid >> 6, lane = tid & 63;
    const int quad = lane >> 4, l16 = lane & 15;
    const int wm = wave & 1, wn = wave >> 1;
    const int mbase = blockIdx.x * 128, nbase = blockIdx.y * 128;
    const int z = blockIdx.z;

    const bf16_t* X   = (z == 0) ? qb : (z == 1) ? kb : vb;
    const float* bias = (z == 0) ? bq : (z == 1) ? bk : bv;
    const bf16_t* W   = Wb + ((size_t)z << 18);

    f32x4 acc[4][4] = {};
    gemm128_core(X, W, mbase, nbase, Asm, Bsm, acc);

    bf16_t* out = (z == 0) ? Qp : (z == 1) ? Kp : Vt;
    #pragma unroll
    for (int mt = 0; mt < 4; ++mt) {
        #pragma unroll
        for (int nt = 0; nt < 4; ++nt) {
            #pragma unroll
            for (int r = 0; r < 4; ++r) {
                int m = mbase + wm * 64 + mt * 16 + quad * 4 + r;  // token index
                int n = nbase + wn * 64 + nt * 16 + l16;           // output channel
                float val = acc[mt][nt][r] + bias[n];
                int b = m >> 10, t = m & 1023, h = n >> 6, hd = n & 63;
                if (z != 2)
                    out[(((size_t)(b * H_ + h) * TA_) + t) * HD_ + hd] = (bf16_t)val;
                else
                    out[((size_t)(b * H_ + h) * HD_ + hd) * TV_ + t] = (bf16_t)val;
            }
        }
    }
}

// ---- Flash attention, in-block split-K, S^T formulation. 512 threads.
// Waves 0-3: k-tiles 0-7; waves 4-7: k-tiles 8-15 (independent K/V LDS halves).
// S^T frag: q=l16, k=16ct+4quad+r -> per-lane softmax + register P -> 16x16x16 PV.
// Final: half-1 dumps fp32 O/m/l into dead Ksm space; half-0 merges, writes ctx.
__global__ __launch_bounds__(512, 4) void attn_kernel(
    const bf16_t* __restrict__ Qp, const bf16_t* __restrict__ Kp,
    const bf16_t* __restrict__ Vt, const hf16_t* __restrict__ bias_t,
    const float* __restrict__ bias_scale, bf16_t* __restrict__ ctx)
{
    __shared__ bf16_t Ksm[2][2][64][72];   // [half][buf][krow][hd]
    __shared__ bf16_t Vsm[2][2][64][72];   // [half][buf][hd][kcol]

    const int tid  = threadIdx.x;
    const int wave = tid >> 6, lane = tid & 63;
    const int half = wave >> 2, w4 = wave & 3;
    const int quad = lane >> 4, l16 = lane & 15;
    const int bh = blockIdx.x, b = bh >> 3, h = bh & 7;
    const int q64 = blockIdx.y;
    const int t0 = half * 8;            // first k-tile for this half
    const int qbase = q64 * 64 + w4 * 16;
    const int rsub = lane >> 3, csub = lane & 7;   // staging: 8 rows x 8 chunks of 16B
    // shuffle source lane: same quad, l16' = quad*4+r  (|r at use site)
    const int shsrc = (lane & 48) | ((lane >> 2) & 12);

    const float sp = log1pf(__expf(bias_scale[0]));  // softplus(bias_scale)

    // Q fragments (MFMA B operand: n=l16=q, k=hd)
    bf16x8 aq[2];
    #pragma unroll
    for (int s = 0; s < 2; ++s)
        aq[s] = *(const bf16x8*)(Qp + ((size_t)bh * TA_ + qbase + l16) * HD_ + s * 32 + quad * 8);

    f32x4 o[4] = {};
    float m_ = -1e30f, l_ = 0.f;   // per-lane: q-row l16

    auto issue_kv = [&](int kt, bf16x8 kr[2], bf16x8 vr[2]) {
        const int kbase = kt * 64;
        #pragma unroll
        for (int i = 0; i < 2; ++i) {
            int row = w4 * 16 + i * 8 + rsub;
            kr[i] = *(const bf16x8*)(Kp + ((size_t)bh * TV_ + kbase + row) * HD_ + csub * 8);
            vr[i] = *(const bf16x8*)(Vt + ((size_t)bh * HD_ + row) * TV_ + kbase + csub * 8);
        }
    };
    auto write_kv = [&](int buf, bf16x8 kr[2], bf16x8 vr[2]) {
        #pragma unroll
        for (int i = 0; i < 2; ++i) {
            int row = w4 * 16 + i * 8 + rsub;
            *(bf16x8*)&Ksm[half][buf][row][csub * 8] = kr[i];
            *(bf16x8*)&Vsm[half][buf][row][csub * 8] = vr[i];
        }
    };

    const int tidb = (w4 << 6) | lane;   // 0..255 packet index within (b,kt,q64)
    const hf16_t* bias_base = bias_t + (((size_t)b * 16 * 16 + q64) * 256 + tidb) * 16;
    auto bias_ld = [&](int kt, hf16x8& lo, hf16x8& hi) {
        const hf16_t* bp = bias_base + (size_t)kt * 65536;  // kt stride = 16*256*16
        lo = *(const hf16x8*)bp;
        hi = *(const hf16x8*)(bp + 8);
    };
    // static ring slots: slot0 = even local tiles, slot1 = odd
    hf16x8 b0lo, b0hi, b1lo, b1hi;
    bias_ld(t0, b0lo, b0hi);
    bias_ld(t0 + 1, b1lo, b1hi);

    {
        bf16x8 kr[2], vr[2];
        issue_kv(t0, kr, vr);
        write_kv(0, kr, vr);
    }
    __syncthreads();

    // one K-tile; lk = local tile index (0..7), buf literal, static ring slot refs
    auto tile_body = [&](int lk, int buf, hf16x8& slo, hf16x8& shi) {
        const int kt = t0 + lk;
        bf16x8 krn[2], vrn[2];
        if (lk < 7) issue_kv(kt + 1, krn, vrn);
        hf16x8 clo = slo, chi = shi;
        if (lk < 6) bias_ld(kt + 2, slo, shi);

        // S^T = K . Q^T  (A = K frag from Ksm, B = Q frag)
        f32x4 st[4];
        #pragma unroll
        for (int ct = 0; ct < 4; ++ct) {
            f32x4 acc = {};
            #pragma unroll
            for (int s = 0; s < 2; ++s) {
                bf16x8 bk = *(const bf16x8*)&Ksm[half][buf][ct * 16 + l16][s * 32 + quad * 8];
                acc = __builtin_amdgcn_mfma_f32_16x16x32_bf16(bk, aq[s], acc, 0, 0, 0);
            }
            st[ct] = acc;
        }
        // bias + per-lane softmax over 16 regs (k = 16ct+4quad+r for q = l16)
        float sv[4][4], mx = -1e30f;
        #pragma unroll
        for (int ct = 0; ct < 4; ++ct) {
            #pragma unroll
            for (int r = 0; r < 4; ++r) {
                int idx = ct * 4 + r;
                float lb = (idx < 8) ? (float)clo[idx] : (float)chi[idx - 8];
                float val = fmaf(lb, sp, st[ct][r] * SCALE_);
                sv[ct][r] = val;
                mx = fmaxf(mx, val);
            }
        }
        mx = fmaxf(mx, __shfl_xor(mx, 16, 64));
        mx = fmaxf(mx, __shfl_xor(mx, 32, 64));
        float mn = fmaxf(m_, mx);
        float alpha = __expf(m_ - mn);
        m_ = mn;
        float ls = 0.f;
        #pragma unroll
        for (int ct = 0; ct < 4; ++ct) {
            #pragma unroll
            for (int r = 0; r < 4; ++r) {
                float p = __expf(sv[ct][r] - mn);
                sv[ct][r] = p;
                ls += p;
            }
        }
        ls += __shfl_xor(ls, 16, 64);
        ls += __shfl_xor(ls, 32, 64);
        l_ = l_ * alpha + ls;
        // redistribute alpha to O's C-frag rows (q = quad*4+r) and rescale O
        #pragma unroll
        for (int r = 0; r < 4; ++r) {
            float af = __shfl(alpha, shsrc | r, 64);
            #pragma unroll
            for (int dt = 0; dt < 4; ++dt) o[dt][r] *= af;
        }
        // O += P.V via 16x16x16 MFMA: A = P chunk (regs), B = V chunk (b64 from Vsm)
        #pragma unroll
        for (int ct = 0; ct < 4; ++ct) {
            bf16x4 ap;
            #pragma unroll
            for (int r = 0; r < 4; ++r) ap[r] = (bf16_t)sv[ct][r];
            #pragma unroll
            for (int dt = 0; dt < 4; ++dt) {
                bf16x4 bv = *(const bf16x4*)&Vsm[half][buf][dt * 16 + l16][ct * 16 + quad * 4];
                o[dt] = mfma16_bf16(ap, bv, o[dt]);
            }
        }
        if (lk < 7) write_kv(buf ^ 1, krn, vrn);
        __syncthreads();
    };

    #pragma unroll 1
    for (int kk = 0; kk < 8; kk += 2) {
        tile_body(kk,     0, b0lo, b0hi);
        tile_body(kk + 1, 1, b1lo, b1hi);
    }

    // ---- in-block combine: Ksm is dead; reuse as fp32 buffer [256][18]
    float* cb = (float*)&Ksm[0][0][0][0];
    if (half == 1) {
        float* p = cb + (size_t)tidb * 18;
        #pragma unroll
        for (int dt = 0; dt < 4; ++dt) {
            #pragma unroll
            for (int r = 0; r < 4; ++r) p[dt * 4 + r] = o[dt][r];
        }
        p[16] = m_; p[17] = l_;
    }
    __syncthreads();
    if (half == 0) {
        const float* p = cb + (size_t)tidb * 18;   // half1's same-lane O
        float s0[4], s1[4];
        #pragma unroll
        for (int r = 0; r < 4; ++r) {
            float m0 = __shfl(m_, shsrc | r, 64);
            float l0 = __shfl(l_, shsrc | r, 64);
            const float* pr = cb + (size_t)((w4 << 6) | (shsrc | r)) * 18;
            float m1 = pr[16], l1 = pr[17];
            float mm = fmaxf(m0, m1);
            float e0 = __expf(m0 - mm), e1 = __expf(m1 - mm);
            float L = l0 * e0 + l1 * e1;
            s0[r] = e0 / L; s1[r] = e1 / L;
        }
        #pragma unroll
        for (int dt = 0; dt < 4; ++dt) {
            #pragma unroll
            for (int r = 0; r < 4; ++r) {
                float v = o[dt][r] * s0[r] + p[dt * 4 + r] * s1[r];
                int qrow = q64 * 64 + w4 * 16 + quad * 4 + r;
                ctx[((size_t)b * TA_ + qrow) * D_ + h * HD_ + dt * 16 + l16] = (bf16_t)v;
            }
        }
    }
}

// ---- Fused out-projection + gated residual + LayerNorm.
// Block: 32 tokens x full 512 cols, 512 threads (8 waves; wave = (nh = w>>1,
// tg = w&1): 16 tokens x 128 cols). LN row stats via l16 shuffles + LDS combine.
__global__ __launch_bounds__(512) void gemm_out_ln(
    const bf16_t* __restrict__ ctx, const bf16_t* __restrict__ Wob,
    const float* __restrict__ bo, const float* __restrict__ q,
    const float* __restrict__ gamma, const float* __restrict__ beta,
    const float* __restrict__ gate, float* __restrict__ y)
{
    __shared__ bf16_t Asm[2][32 * 32];    // 2 KB per buf
    __shared__ bf16_t Bsm[2][512 * 32];   // 32 KB per buf
    __shared__ float ps[32][4], psq[32][4];

    const int tid  = threadIdx.x;
    const int wave = tid >> 6, lane = tid & 63;
    const int quad = lane >> 4, l16 = lane & 15;
    const int tg = wave & 1, nh = wave >> 1;
    const int mbase = blockIdx.x * 32;

    auto stage = [&](int kt, int buf) {
        const int k0 = kt * 32;
        #pragma unroll
        for (int j = 0; j < 4; ++j) {
            int row0 = wave * 64 + j * 16;   // B rows [row0, row0+16)
            g2l16(Wob + (size_t)(row0 + (lane >> 2)) * D_ + k0 + (lane & 3) * 8,
                  &Bsm[buf][row0 * 32] + (size_t)lane * 8);
        }
        if (wave < 2) {                      // A rows [wave*16, wave*16+16)
            int row0 = wave * 16;
            g2l16(ctx + (size_t)(mbase + row0 + (lane >> 2)) * D_ + k0 + (lane & 3) * 8,
                  &Asm[buf][row0 * 32] + (size_t)lane * 8);
        }
    };

    f32x4 acc[8] = {};
    stage(0, 0);
    __syncthreads();
    for (int kt = 0; kt < 16; ++kt) {
        const int buf = kt & 1;
        if (kt < 15) stage(kt + 1, buf ^ 1);
        bf16x8 af = *(const bf16x8*)&Asm[buf][(tg * 16 + l16) * 32 + quad * 8];
        #pragma unroll
        for (int nt = 0; nt < 8; ++nt) {
            bf16x8 bf_ = *(const bf16x8*)&Bsm[buf][(nh * 128 + nt * 16 + l16) * 32 + quad * 8];
            acc[nt] = __builtin_amdgcn_mfma_f32_16x16x32_bf16(af, bf_, acc[nt], 0, 0, 0);
        }
        __syncthreads();
    }

    const float sg = 1.f / (1.f + __expf(-gate[0]));
    // x = q + sg*(acc + bo); keep x in acc; accumulate row partials (128 cols/wave)
    float s[4] = {0.f, 0.f, 0.f, 0.f}, sq[4] = {0.f, 0.f, 0.f, 0.f};
    #pragma unroll
    for (int nt = 0; nt < 8; ++nt) {
        int n = nh * 128 + nt * 16 + l16;
        float bon = bo[n];
        #pragma unroll
        for (int r = 0; r < 4; ++r) {
            int m = mbase + tg * 16 + quad * 4 + r;
            float x = q[(size_t)m * D_ + n] + sg * (acc[nt][r] + bon);
            acc[nt][r] = x;
            s[r] += x; sq[r] += x * x;
        }
    }
    #pragma unroll
    for (int off = 1; off < 16; off <<= 1) {
        #pragma unroll
        for (int r = 0; r < 4; ++r) {
            s[r]  += __shfl_xor(s[r],  off, 64);
            sq[r] += __shfl_xor(sq[r], off, 64);
        }
    }
    if (l16 == 0) {
        #pragma unroll
        for (int r = 0; r < 4; ++r) {
            ps[tg * 16 + quad * 4 + r][nh]  = s[r];
            psq[tg * 16 + quad * 4 + r][nh] = sq[r];
        }
    }
    __syncthreads();
    float mu[4], rstd[4];
    #pragma unroll
    for (int r = 0; r < 4; ++r) {
        int row = tg * 16 + quad * 4 + r;
        float S  = ps[row][0] + ps[row][1] + ps[row][2] + ps[row][3];
        float SQ = psq[row][0] + psq[row][1] + psq[row][2] + psq[row][3];
        mu[r] = S * (1.f / D_);
        float var = SQ * (1.f / D_) - mu[r] * mu[r];
        rstd[r] = rsqrtf(var + 1e-5f);
    }
    #pragma unroll
    for (int nt = 0; nt < 8; ++nt) {
        int n = nh * 128 + nt * 16 + l16;
        float gn = gamma[n], bn = beta[n];
        #pragma unroll
        for (int r = 0; r < 4; ++r) {
            int m = mbase + tg * 16 + quad * 4 + r;
            y[(size_t)m * D_ + n] = (acc[nt][r] - mu[r]) * rstd[r] * gn + bn;
        }
    }
}

extern "C" void kernel_launch(void* const* d_in, const int* in_sizes, int n_in,
                              void* d_out, int out_size, void* d_ws, size_t ws_size,
                              hipStream_t stream) {
    const float* q       = (const float*)d_in[0];
    const float* k       = (const float*)d_in[1];
    const float* v       = (const float*)d_in[2];
    const float* guide   = (const float*)d_in[3];
    const float* Wq      = (const float*)d_in[4];
    const float* bq      = (const float*)d_in[5];
    const float* Wk      = (const float*)d_in[6];
    const float* bk      = (const float*)d_in[7];
    const float* Wv      = (const float*)d_in[8];
    const float* bv      = (const float*)d_in[9];
    const float* Wo      = (const float*)d_in[10];
    const float* bo      = (const float*)d_in[11];
    const float* gamma   = (const float*)d_in[12];
    const float* beta    = (const float*)d_in[13];
    const float* gate    = (const float*)d_in[14];
    const float* bscale  = (const float*)d_in[15];

    char* w = (char*)d_ws;
    bf16_t* qb     = (bf16_t*)(w);                  // 4 MB bf16 [4096,512]
    bf16_t* kb     = (bf16_t*)(w + (4u  << 20));    // 4 MB
    bf16_t* vb     = (bf16_t*)(w + (8u  << 20));    // 4 MB
    bf16_t* Wb     = (bf16_t*)(w + (12u << 20));    // 2 MB concat Wq,Wk,Wv,Wo bf16
    bf16_t* Qp     = (bf16_t*)(w + (14u << 20));    // 4 MB [B,H,TA,HD]
    bf16_t* Kp     = (bf16_t*)(w + (18u << 20));    // 4 MB [B,H,TV,HD]
    bf16_t* Vt     = (bf16_t*)(w + (22u << 20));    // 4 MB [B,H,HD,TV]
    bf16_t* ctx    = (bf16_t*)(w + (26u << 20));    // 4 MB [B,TA,D]
    hf16_t* bias_t = (hf16_t*)(w + (30u << 20));    // 8 MB tiled fp16

    prep_all<<<4608, 256, 0, stream>>>(guide, bias_t, q, k, v, Wq, Wk, Wv, Wo, qb, kb, vb, Wb);
    gemm_qkv<<<dim3(32, 4, 3), 256, 0, stream>>>(qb, kb, vb, Wb, bq, bk, bv, Qp, Kp, Vt);
    attn_kernel<<<dim3(32, 16), 512, 0, stream>>>(Qp, Kp, Vt, bias_t, bscale, ctx);
    gemm_out_ln<<<128, 512, 0, stream>>>(ctx, Wb + ((size_t)3 << 18), bo, q,
                                         gamma, beta, gate, (float*)d_out);
}